// Round 17
// baseline (426.140 us; speedup 1.0000x reference)
//
#include <hip/hip_runtime.h>
#include <stdint.h>

typedef __attribute__((ext_vector_type(8))) short bf16x8;
typedef __attribute__((ext_vector_type(4))) short bf16x4;
typedef __attribute__((ext_vector_type(4))) float f32x4;

__device__ __forceinline__ short f2bf(float f) {
    union { float f; unsigned u; } v; v.f = f;
    unsigned r = v.u + 0x7fffu + ((v.u >> 16) & 1u);
    return (short)(r >> 16);
}
__device__ __forceinline__ float bf2f(short s) {
    union { unsigned u; float f; } v;
    v.u = ((unsigned)(unsigned short)s) << 16;
    return v.f;
}

__device__ __forceinline__ void gld16(const void* g, void* l) {
    auto gp = reinterpret_cast<const __attribute__((address_space(1))) unsigned int*>(
        reinterpret_cast<uintptr_t>(g));
    auto lp = reinterpret_cast<__attribute__((address_space(3))) unsigned int*>(
        reinterpret_cast<uintptr_t>(l));
    __builtin_amdgcn_global_load_lds(gp, lp, 16, 0, 0);
}

// ---------------------------------------------------------------------------
// gemmTN: Pt_half[s,d] = sum_{c in half} score_c[c,s] * knoT[d,c].
// (verified round 16) K-split x2 via zhi, fp32 partials, grid (3,16,16).
// ---------------------------------------------------------------------------
__global__ __launch_bounds__(256, 3) void gemmTN(
    const float* __restrict__ Ag, const short* __restrict__ Bg,
    float* __restrict__ Cg,
    long long sA, long long sB, long long sC, long long dC)
{
    __shared__ short lds[2 * 8256];   // per buf: A 4160 (8 quads x 520) | B 4096
    const int t = threadIdx.x;
    const int lane = t & 63;
    const int wave = t >> 6;
    const int wm = wave >> 1, wn = wave & 1;

    const int nwg = 3 * 16 * 16;
    int id = blockIdx.x + 3 * (blockIdx.y + 16 * blockIdx.z);
    id = (id & 7) * (nwg >> 3) + (id >> 3);
    const int bx = id % 3;
    const int by = (id / 3) % 16;
    const int bzz = id / 48;
    const int zlo = bzz & 7, zhi = bzz >> 3;

    const long long s0 = (long long)by * 128;
    const int d0 = bx * 128;
    const int q = t >> 5, kk = t & 31;
    const float* Asrc = Ag + zlo * sA + (long long)zhi * 1024 * 2048
                        + (long long)(q * 4) * 2048 + s0 + kk * 4;

    const int gk = ((t & 3) ^ ((t >> 2) & 3) ^ ((t >> 4) & 3)) * 8;
    const short* Bsrc = Bg + zlo * sB + zhi * 1024 + (d0 + (t >> 2)) * 2048LL + gk;

    const int frow = lane & 15;
    const int g = lane >> 4;
    const int fcol = (g ^ (frow & 3) ^ ((frow >> 2) & 3)) * 8;

    f32x4 acc[4][4] = {};
    f32x4 ar[4];

#define STAGE_B(BUF, KC) do { \
        gld16(Bsrc + (KC), &lds[(BUF) + 4160 + t * 8]); \
        gld16(Bsrc + (KC) + 64LL * 2048, &lds[(BUF) + 4160 + 2048 + t * 8]); } while (0)

#define WRITE_A(BUF) do { \
        short tmp[16]; \
        _Pragma("unroll") \
        for (int i = 0; i < 16; ++i) tmp[i] = f2bf(ar[i & 3][i >> 2]); \
        short* dst = &lds[(BUF) + q * 520 + kk * 16]; \
        *(bf16x8*)dst = *(bf16x8*)&tmp[0]; \
        *(bf16x8*)(dst + 8) = *(bf16x8*)&tmp[8]; } while (0)

#pragma unroll
    for (int r = 0; r < 4; ++r) ar[r] = *(const f32x4*)&Asrc[(long long)r * 2048];
    STAGE_B(0, 0);
    WRITE_A(0);
    asm volatile("s_waitcnt vmcnt(0) lgkmcnt(0)\ns_barrier" ::: "memory");
#pragma unroll
    for (int r = 0; r < 4; ++r) ar[r] = *(const f32x4*)&Asrc[65536LL + r * 2048];

    const int NT = 32;   // K-half = 1024, BK = 32
    for (int kt = 0; kt < NT; ++kt) {
        const int rb = (kt & 1) * 8256;
        const int wb = ((kt + 1) & 1) * 8256;

        bf16x8 av[4], bv[4];
#pragma unroll
        for (int m = 0; m < 4; ++m) {
            const int sl = (wm * 64 + m * 16 + frow) * 4;
            bf16x4 lo = *(const bf16x4*)&lds[rb + 1040 * g + sl];
            bf16x4 hi = *(const bf16x4*)&lds[rb + 1040 * g + 520 + sl];
            av[m] = __builtin_shufflevector(lo, hi, 0, 1, 2, 3, 4, 5, 6, 7);
        }
#pragma unroll
        for (int n = 0; n < 4; ++n)
            bv[n] = *(const bf16x8*)&lds[rb + 4160 + (wn * 64 + n * 16 + frow) * 32 + fcol];

        if (kt + 1 < NT) {
            STAGE_B(wb, (long long)(kt + 1) * 32);
            WRITE_A(wb);
        }
#pragma unroll
        for (int m = 0; m < 4; ++m)
#pragma unroll
            for (int n = 0; n < 4; ++n)
                acc[m][n] = __builtin_amdgcn_mfma_f32_16x16x32_bf16(av[m], bv[n], acc[m][n], 0, 0, 0);
        if (kt + 1 < NT) {
            asm volatile("s_waitcnt vmcnt(0) lgkmcnt(0)\ns_barrier" ::: "memory");
            if (kt + 2 < NT) {
#pragma unroll
                for (int r = 0; r < 4; ++r)
                    ar[r] = *(const f32x4*)&Asrc[(long long)(kt + 2) * 65536 + r * 2048];
            }
        }
    }
#undef STAGE_B
#undef WRITE_A

    const int crow = (lane >> 4) * 4;
    const int ccol = lane & 15;
    const long long cz = zlo * sC + zhi * dC;
#pragma unroll
    for (int m = 0; m < 4; ++m)
#pragma unroll
        for (int n = 0; n < 4; ++n)
#pragma unroll
            for (int i = 0; i < 4; ++i) {
                long long r = s0 + wm * 64 + m * 16 + crow + i;
                long long c = d0 + wn * 64 + n * 16 + ccol;
                Cg[cz + r * 384 + c] = acc[m][n][i];
            }
}

// combine K-split fp32 halves -> bf16: out[i] = bf16(p[i] + p[i+half])
__global__ __launch_bounds__(256) void combine_bf(
    const float* __restrict__ p, long long half, short* __restrict__ out)
{
    long long i = ((long long)blockIdx.x * 256 + threadIdx.x) * 4;
    if (i + 3 < half) {
        float4 a = *(const float4*)&p[i];
        float4 b = *(const float4*)&p[i + half];
        short4 o;
        o.x = f2bf(a.x + b.x); o.y = f2bf(a.y + b.y);
        o.z = f2bf(a.z + b.z); o.w = f2bf(a.w + b.w);
        *(short4*)&out[i] = o;
    }
}

// ---------------------------------------------------------------------------
// gemmWide: 128x256 NT GEMM, BK=32, 4 waves (2x2), wave-tile 64x128.
// Ring-3 LDS (72 KiB -> 2 blocks/CU), stage distance 2, counted vmcnt(6).
// NEW: LDS-staged coalesced epilogue (OUTBF path): acc -> LDS [128][260]
// (quarter-waves on disjoint bank octets) -> 16x b128 global stores/thread,
// 1KB contiguous per wave (full-burst HBM writes vs 32B scalar granules).
// GRID CONTRACT: gy*128 == rows PER BATCH-PLANE (z).
// ---------------------------------------------------------------------------
template<int OUTBF, int BIASMODE /*0 none,1 col*/, int DORELU>
__global__ __launch_bounds__(256, 2) void gemmWide(
    const short* __restrict__ Ag, const short* __restrict__ Bg,
    void* __restrict__ Cg, const float* __restrict__ bias,
    int K, int lda, int ldb, int ldc,
    long long sA, long long sB, long long sC,
    long long dA, long long dB, long long dC, float scale)
{
    __shared__ short lds[3 * 12288];
    const int t = threadIdx.x;
    const int lane = t & 63;
    const int wave = t >> 6;
    const int wm = wave >> 1, wn = wave & 1;

    const int gx = gridDim.x, gy = gridDim.y;
    const int nwg = gx * gy * gridDim.z;
    int id = blockIdx.x + gx * (blockIdx.y + gy * blockIdx.z);
    id = (id & 7) * (nwg >> 3) + (id >> 3);
    const int bx = id % gx;
    const int by = (id / gx) % gy;
    const int bz = id / (gx * gy);
    const int zlo = bz & 7, zhi = bz >> 3;

    const long long row0 = (long long)by * 128;
    const long long col0 = (long long)bx * 256;
    const int NT = K >> 5;

    const int gk = ((t & 3) ^ ((t >> 2) & 3) ^ ((t >> 4) & 3)) * 8;
    const short* Asrc = Ag + zlo * sA + zhi * dA + (row0 + (t >> 2)) * (long long)lda + gk;
    const short* Bsrc = Bg + zlo * sB + zhi * dB + (col0 + (t >> 2)) * (long long)ldb + gk;

    const int frow = lane & 15;
    const int fcol = ((lane >> 4) ^ (frow & 3) ^ ((frow >> 2) & 3)) * 8;

    f32x4 acc[4][8] = {};

#define STG(BUF, KC) do { \
        gld16(Asrc + (KC), &lds[(BUF) * 12288 + t * 8]); \
        gld16(Asrc + (KC) + 64LL * lda, &lds[(BUF) * 12288 + 2048 + t * 8]); \
        gld16(Bsrc + (KC), &lds[(BUF) * 12288 + 4096 + t * 8]); \
        gld16(Bsrc + (KC) + 64LL * ldb, &lds[(BUF) * 12288 + 6144 + t * 8]); \
        gld16(Bsrc + (KC) + 128LL * ldb, &lds[(BUF) * 12288 + 8192 + t * 8]); \
        gld16(Bsrc + (KC) + 192LL * ldb, &lds[(BUF) * 12288 + 10240 + t * 8]); } while (0)

    STG(0, 0);
    STG(1, 32);
    asm volatile("s_waitcnt vmcnt(6)\ns_barrier" ::: "memory");

    for (int kt = 0; kt < NT; ++kt) {
        const int rb = (kt % 3) * 12288;
        bf16x8 av[4], bv[8];
#pragma unroll
        for (int m = 0; m < 4; ++m)
            av[m] = *(const bf16x8*)&lds[rb + (wm * 64 + m * 16 + frow) * 32 + fcol];
#pragma unroll
        for (int n = 0; n < 8; ++n)
            bv[n] = *(const bf16x8*)&lds[rb + 4096 + (wn * 128 + n * 16 + frow) * 32 + fcol];
        if (kt + 2 < NT) STG((kt + 2) % 3, (long long)(kt + 2) * 32);
        __builtin_amdgcn_s_setprio(1);
#pragma unroll
        for (int m = 0; m < 4; ++m)
#pragma unroll
            for (int n = 0; n < 8; ++n)
                acc[m][n] = __builtin_amdgcn_mfma_f32_16x16x32_bf16(av[m], bv[n], acc[m][n], 0, 0, 0);
        __builtin_amdgcn_s_setprio(0);
        if (kt + 1 < NT) {
            if (kt + 2 < NT) asm volatile("s_waitcnt vmcnt(6)\ns_barrier" ::: "memory");
            else             asm volatile("s_waitcnt vmcnt(0)\ns_barrier" ::: "memory");
        }
    }
#undef STG

    const int crow = (lane >> 4) * 4;
    const int ccol = lane & 15;
    const long long cz = zlo * sC + zhi * dC;

    if (OUTBF) {
        // staged epilogue: acc -> LDS [128][260] -> coalesced b128 stores
        __syncthreads();   // all ring reads complete before overwrite
#pragma unroll
        for (int m = 0; m < 4; ++m)
#pragma unroll
            for (int n = 0; n < 8; ++n)
#pragma unroll
                for (int i = 0; i < 4; ++i) {
                    int rr = wm * 64 + m * 16 + crow + i;
                    int cc = wn * 128 + n * 16 + ccol;
                    float v = acc[m][n][i] * scale;
                    if (BIASMODE == 1) v += bias[col0 + cc];
                    if (DORELU) v = fmaxf(v, 0.0f);
                    lds[rr * 260 + cc] = f2bf(v);
                }
        __syncthreads();
        short* outp = (short*)Cg;
#pragma unroll
        for (int j = 0; j < 16; ++j) {
            int flat = j * 2048 + t * 8;
            int rr = flat >> 8;
            int cc = flat & 255;
            bf16x8 v = *(const bf16x8*)&lds[rr * 260 + cc];
            *(bf16x8*)&outp[cz + (row0 + rr) * (long long)ldc + col0 + cc] = v;
        }
    } else {
#pragma unroll
        for (int m = 0; m < 4; ++m)
#pragma unroll
            for (int n = 0; n < 8; ++n)
#pragma unroll
                for (int i = 0; i < 4; ++i) {
                    long long r = row0 + wm * 64 + m * 16 + crow + i;
                    long long c = col0 + wn * 128 + n * 16 + ccol;
                    float v = acc[m][n][i] * scale;
                    if (BIASMODE == 1) v += bias[c];
                    if (DORELU) v = fmaxf(v, 0.0f);
                    ((float*)Cg)[cz + r * (long long)ldc + c] = v;
                }
    }
}

// ---------------------------------------------------------------------------
// gemm128r: 128x128 NT GEMM, BK=32, ring-3 (verified round 7).
// ---------------------------------------------------------------------------
template<int OUTBF, int BIASMODE /*0 none,1 col,2 row*/, int DORELU>
__global__ __launch_bounds__(256, 3) void gemm128r(
    const short* __restrict__ Ag, const short* __restrict__ Bg,
    void* __restrict__ Cg, const float* __restrict__ bias,
    int K, int lda, int ldb, int ldc,
    long long sA, long long sB, long long sC,
    long long dA, long long dB, long long dC, float scale)
{
    __shared__ short lds[3 * 8192];
    const int t = threadIdx.x;
    const int lane = t & 63;
    const int wave = t >> 6;
    const int wm = wave >> 1, wn = wave & 1;

    const int gx = gridDim.x, gy = gridDim.y;
    const int nwg = gx * gy * gridDim.z;
    int id = blockIdx.x + gx * (blockIdx.y + gy * blockIdx.z);
    id = (id & 7) * (nwg >> 3) + (id >> 3);
    const int bx = id % gx;
    const int by = (id / gx) % gy;
    const int bz = id / (gx * gy);
    const int zlo = bz & 7, zhi = bz >> 3;

    const long long row0 = (long long)by * 128;
    const long long col0 = (long long)bx * 128;
    const int NT = K >> 5;

    const int gk = ((t & 3) ^ ((t >> 2) & 3) ^ ((t >> 4) & 3)) * 8;
    const short* Asrc = Ag + zlo * sA + zhi * dA + (row0 + (t >> 2)) * (long long)lda + gk;
    const short* Bsrc = Bg + zlo * sB + zhi * dB + (col0 + (t >> 2)) * (long long)ldb + gk;

    const int frow = lane & 15;
    const int fcol = ((lane >> 4) ^ (frow & 3) ^ ((frow >> 2) & 3)) * 8;

    f32x4 acc[4][4] = {};

#define STG(BUF, KC) do { \
        gld16(Asrc + (KC), &lds[(BUF) * 8192 + t * 8]); \
        gld16(Asrc + (KC) + 64LL * lda, &lds[(BUF) * 8192 + 2048 + t * 8]); \
        gld16(Bsrc + (KC), &lds[(BUF) * 8192 + 4096 + t * 8]); \
        gld16(Bsrc + (KC) + 64LL * ldb, &lds[(BUF) * 8192 + 6144 + t * 8]); } while (0)

    STG(0, 0);
    STG(1, 32);
    asm volatile("s_waitcnt vmcnt(4)\ns_barrier" ::: "memory");

    for (int kt = 0; kt < NT; ++kt) {
        const int rb = (kt % 3) * 8192;
        bf16x8 av[4], bv[4];
#pragma unroll
        for (int m = 0; m < 4; ++m)
            av[m] = *(const bf16x8*)&lds[rb + (wm * 64 + m * 16 + frow) * 32 + fcol];
#pragma unroll
        for (int n = 0; n < 4; ++n)
            bv[n] = *(const bf16x8*)&lds[rb + 4096 + (wn * 64 + n * 16 + frow) * 32 + fcol];
        if (kt + 2 < NT) STG((kt + 2) % 3, (long long)(kt + 2) * 32);
        __builtin_amdgcn_s_setprio(1);
#pragma unroll
        for (int m = 0; m < 4; ++m)
#pragma unroll
            for (int n = 0; n < 4; ++n)
                acc[m][n] = __builtin_amdgcn_mfma_f32_16x16x32_bf16(av[m], bv[n], acc[m][n], 0, 0, 0);
        __builtin_amdgcn_s_setprio(0);
        if (kt + 1 < NT) {
            if (kt + 2 < NT) asm volatile("s_waitcnt vmcnt(4)\ns_barrier" ::: "memory");
            else             asm volatile("s_waitcnt vmcnt(0)\ns_barrier" ::: "memory");
        }
    }
#undef STG

    const int crow = (lane >> 4) * 4;
    const int ccol = lane & 15;
    const long long cz = zlo * sC + zhi * dC;
#pragma unroll
    for (int m = 0; m < 4; ++m)
#pragma unroll
        for (int n = 0; n < 4; ++n)
#pragma unroll
            for (int i = 0; i < 4; ++i) {
                long long r = row0 + wm * 64 + m * 16 + crow + i;
                long long c = col0 + wn * 64 + n * 16 + ccol;
                float v = acc[m][n][i] * scale;
                if (BIASMODE == 1) v += bias[c];
                if (BIASMODE == 2) v += bias[r];
                if (DORELU) v = fmaxf(v, 0.0f);
                long long idx = cz + r * (long long)ldc + c;
                if (OUTBF) ((short*)Cg)[idx] = f2bf(v);
                else ((float*)Cg)[idx] = v;
            }
}

// ---------------------------------------------------------------------------
// gemm128rr: bx-keyed dual 128r (qu: bx<6, k: bx>=6). Grid (9,128,1).
// ---------------------------------------------------------------------------
__global__ __launch_bounds__(256, 3) void gemm128rr(
    const short* __restrict__ A1, const short* __restrict__ B1,
    short* __restrict__ C1, const float* __restrict__ bias1,
    int K1, int lda1, int ldb1, int ldc1,
    const short* __restrict__ A2, const short* __restrict__ B2,
    short* __restrict__ C2, const float* __restrict__ bias2,
    int K2, int lda2, int ldb2, int ldc2)
{
    __shared__ short lds[3 * 8192];
    const int t = threadIdx.x;
    const int lane = t & 63;
    const int wave = t >> 6;
    const int wm = wave >> 1, wn = wave & 1;

    const int gx = gridDim.x, gy = gridDim.y;
    const int nwg = gx * gy;
    int id = blockIdx.x + gx * blockIdx.y;
    id = (id & 7) * (nwg >> 3) + (id >> 3);
    const int bx = id % gx;
    const int by = id / gx;

    const bool sel = bx >= 6;
    const int bxx = sel ? bx - 6 : bx;
    const short* Ag = sel ? A2 : A1;
    const short* Bg = sel ? B2 : B1;
    short* Cg = sel ? C2 : C1;
    const float* bias = sel ? bias2 : bias1;
    const int K = sel ? K2 : K1;
    const int lda = sel ? lda2 : lda1;
    const int ldb = sel ? ldb2 : ldb1;
    const int ldc = sel ? ldc2 : ldc1;

    const long long row0 = (long long)by * 128;
    const long long col0 = (long long)bxx * 128;
    const int NT = K >> 5;

    const int gk = ((t & 3) ^ ((t >> 2) & 3) ^ ((t >> 4) & 3)) * 8;
    const short* Asrc = Ag + (row0 + (t >> 2)) * (long long)lda + gk;
    const short* Bsrc = Bg + (col0 + (t >> 2)) * (long long)ldb + gk;

    const int frow = lane & 15;
    const int fcol = ((lane >> 4) ^ (frow & 3) ^ ((frow >> 2) & 3)) * 8;

    f32x4 acc[4][4] = {};

#define STG(BUF, KC) do { \
        gld16(Asrc + (KC), &lds[(BUF) * 8192 + t * 8]); \
        gld16(Asrc + (KC) + 64LL * lda, &lds[(BUF) * 8192 + 2048 + t * 8]); \
        gld16(Bsrc + (KC), &lds[(BUF) * 8192 + 4096 + t * 8]); \
        gld16(Bsrc + (KC) + 64LL * ldb, &lds[(BUF) * 8192 + 6144 + t * 8]); } while (0)

    STG(0, 0);
    STG(1, 32);
    asm volatile("s_waitcnt vmcnt(4)\ns_barrier" ::: "memory");

    for (int kt = 0; kt < NT; ++kt) {
        const int rb = (kt % 3) * 8192;
        bf16x8 av[4], bv[4];
#pragma unroll
        for (int m = 0; m < 4; ++m)
            av[m] = *(const bf16x8*)&lds[rb + (wm * 64 + m * 16 + frow) * 32 + fcol];
#pragma unroll
        for (int n = 0; n < 4; ++n)
            bv[n] = *(const bf16x8*)&lds[rb + 4096 + (wn * 64 + n * 16 + frow) * 32 + fcol];
        if (kt + 2 < NT) STG((kt + 2) % 3, (long long)(kt + 2) * 32);
        __builtin_amdgcn_s_setprio(1);
#pragma unroll
        for (int m = 0; m < 4; ++m)
#pragma unroll
            for (int n = 0; n < 4; ++n)
                acc[m][n] = __builtin_amdgcn_mfma_f32_16x16x32_bf16(av[m], bv[n], acc[m][n], 0, 0, 0);
        __builtin_amdgcn_s_setprio(0);
        if (kt + 1 < NT) {
            if (kt + 2 < NT) asm volatile("s_waitcnt vmcnt(4)\ns_barrier" ::: "memory");
            else             asm volatile("s_waitcnt vmcnt(0)\ns_barrier" ::: "memory");
        }
    }
#undef STG

    const int crow = (lane >> 4) * 4;
    const int ccol = lane & 15;
#pragma unroll
    for (int m = 0; m < 4; ++m)
#pragma unroll
        for (int n = 0; n < 4; ++n)
#pragma unroll
            for (int i = 0; i < 4; ++i) {
                long long r = row0 + wm * 64 + m * 16 + crow + i;
                long long c = col0 + wn * 64 + n * 16 + ccol;
                float v = acc[m][n][i] + bias[c];
                Cg[r * (long long)ldc + c] = f2bf(v);
            }
}

// ---------------------------------------------------------------------------
// gemm128pz: dual-parameter 2-phase engine (verified round 6), z<8 -> vT,
// z>=8 -> knoT. Both: C = A @ B^T + rowbias, A = weight.
// ---------------------------------------------------------------------------
#define RD_A(RB, M, KS) (*(const bf16x8*)&lds[(RB) + (wm * 64 + (M) * 16 + frow) * 64 + \
        ((((KS) << 2) | fq) ^ (frow & 7)) * 8])
#define RD_B(RB, Nn, KS) (*(const bf16x8*)&lds[(RB) + 8192 + (wn * 64 + (Nn) * 16 + frow) * 64 + \
        ((((KS) << 2) | fq) ^ (frow & 7)) * 8])

__global__ __launch_bounds__(256, 2) void gemm128pz(
    const short* __restrict__ A1, const short* __restrict__ B1, short* __restrict__ C1,
    const float* __restrict__ bias1, int K1, int lda1, int ldb1, int ldc1,
    long long sB1, long long sC1,
    const short* __restrict__ A2, const short* __restrict__ B2, short* __restrict__ C2,
    const float* __restrict__ bias2, int K2, int lda2, int ldb2, int ldc2,
    long long sB2, long long sC2)
{
    __shared__ short lds[2 * 16384];
    const int t = threadIdx.x;
    const int lane = t & 63;
    const int wave = t >> 6;
    const int wm = wave >> 1, wn = wave & 1;

    const int gx = gridDim.x, gy = gridDim.y;
    const int nwg = gx * gy * gridDim.z;
    int id = blockIdx.x + gx * (blockIdx.y + gy * blockIdx.z);
    id = (id & 7) * (nwg >> 3) + (id >> 3);
    const int bx = id % gx;
    const int by = (id / gx) % gy;
    const int bz = id / (gx * gy);

    const bool sel = bz >= 8;
    const int zz = bz & 7;
    const short* Ag = sel ? A2 : A1;
    const short* Bg = sel ? B2 : B1;
    short* Cg = sel ? C2 : C1;
    const float* bias = sel ? bias2 : bias1;
    const int K = sel ? K2 : K1;
    const int lda = sel ? lda2 : lda1;
    const int ldb = sel ? ldb2 : ldb1;
    const int ldc = sel ? ldc2 : ldc1;
    const long long sB = sel ? sB2 : sB1;
    const long long sC = sel ? sC2 : sC1;

    const long long row0 = (long long)by * 128;
    const long long col0 = (long long)bx * 128;
    const int NT = K >> 6;

    const int srow = t >> 3;
    const int gk = ((t & 7) ^ (srow & 7)) * 8;
    const short* Asrc = Ag + (row0 + srow) * (long long)lda + gk;
    const short* Bsrc = Bg + (long long)zz * sB + (col0 + srow) * (long long)ldb + gk;

    const int frow = lane & 15;
    const int fq = lane >> 4;

    f32x4 acc[4][4] = {};

#define STAGE_A(WB, KC) do { _Pragma("unroll") \
        for (int r = 0; r < 4; ++r) \
            gld16(Asrc + (KC) + (long long)r * 32 * lda, &lds[(WB) + t * 8 + r * 2048]); } while (0)
#define STAGE_B(WB, KC) do { _Pragma("unroll") \
        for (int r = 0; r < 4; ++r) \
            gld16(Bsrc + (KC) + (long long)r * 32 * ldb, &lds[(WB) + 8192 + t * 8 + r * 2048]); } while (0)

    STAGE_A(0, 0);
    STAGE_B(0, 0);
    asm volatile("s_waitcnt vmcnt(0)\ns_barrier" ::: "memory");

    for (int kt = 0; kt < NT; ++kt) {
        const int rb = (kt & 1) << 14;
        const int wb = ((kt + 1) & 1) << 14;
        const bool st = (kt + 1) < NT;
        const long long kc = (long long)(kt + 1) << 6;

        bf16x8 av[4], bv[4];

#pragma unroll
        for (int m = 0; m < 4; ++m) av[m] = RD_A(rb, m, 0);
#pragma unroll
        for (int n = 0; n < 4; ++n) bv[n] = RD_B(rb, n, 0);
        if (st) STAGE_A(wb, kc);
        asm volatile("s_barrier" ::: "memory");
        __builtin_amdgcn_s_setprio(1);
#pragma unroll
        for (int m = 0; m < 4; ++m)
#pragma unroll
            for (int n = 0; n < 4; ++n)
                acc[m][n] = __builtin_amdgcn_mfma_f32_16x16x32_bf16(av[m], bv[n], acc[m][n], 0, 0, 0);
        __builtin_amdgcn_s_setprio(0);
        asm volatile("s_barrier" ::: "memory");

#pragma unroll
        for (int m = 0; m < 4; ++m) av[m] = RD_A(rb, m, 1);
#pragma unroll
        for (int n = 0; n < 4; ++n) bv[n] = RD_B(rb, n, 1);
        if (st) STAGE_B(wb, kc);
        asm volatile("s_barrier" ::: "memory");
        __builtin_amdgcn_s_setprio(1);
#pragma unroll
        for (int m = 0; m < 4; ++m)
#pragma unroll
            for (int n = 0; n < 4; ++n)
                acc[m][n] = __builtin_amdgcn_mfma_f32_16x16x32_bf16(av[m], bv[n], acc[m][n], 0, 0, 0);
        __builtin_amdgcn_s_setprio(0);
        if (st) asm volatile("s_waitcnt vmcnt(0)\ns_barrier" ::: "memory");
        else    asm volatile("s_barrier" ::: "memory");
    }
#undef STAGE_A
#undef STAGE_B

    const int crow = (lane >> 4) * 4;
    const int ccol = lane & 15;
    const long long cz = (long long)zz * sC;
#pragma unroll
    for (int m = 0; m < 4; ++m)
#pragma unroll
        for (int n = 0; n < 4; ++n)
#pragma unroll
            for (int i = 0; i < 4; ++i) {
                long long r = row0 + wm * 64 + m * 16 + crow + i;
                long long c = col0 + wn * 64 + n * 16 + ccol;
                float v = acc[m][n][i] + bias[r];
                Cg[cz + r * (long long)ldc + c] = f2bf(v);
            }
}
#undef RD_A
#undef RD_B

// ---------------------------------------------------------------------------
// prologue v3: [0,4096) cast 4xfloat4/thread | 4096 bias | [4097,4541) weight
// transposes (64x64). score_c transpose ELIMINATED (gemmTN reads it directly).
// ---------------------------------------------------------------------------
__global__ __launch_bounds__(256) void prologue(
    const float* __restrict__ tgt, const float* __restrict__ mem, const float* __restrict__ outc,
    const float* __restrict__ bq, const float* __restrict__ bu,
    short* __restrict__ tgtb, short* __restrict__ memb, short* __restrict__ outcb,
    float* __restrict__ qubias,
    const float* __restrict__ Wq, const float* __restrict__ Wk, const float* __restrict__ Wv,
    const float* __restrict__ Wu, const float* __restrict__ Wn,
    const float* __restrict__ W1, const float* __restrict__ W2,
    short* __restrict__ WquT, short* __restrict__ WkT, short* __restrict__ WvT,
    short* __restrict__ WnT, short* __restrict__ W1T, short* __restrict__ W2T)
{
    __shared__ float tile[64][65];
    const int blk = blockIdx.x;
    const int t = threadIdx.x;

    if (blk < 4096) {
        const long long R1 = 1572864;
        const long long R2 = R1 + 1048576;
        const long long base = (long long)blk * 1024 + t;
#pragma unroll
        for (int s = 0; s < 4; ++s) {
            long long i = base + s * 256;
            const float* in; short* out; long long j;
            if (i < R1) { in = tgt; out = tgtb; j = i; }
            else if (i < R2) { in = mem; out = memb; j = i - R1; }
            else { in = outc; out = outcb; j = i - R2; }
            float4 v = ((const float4*)in)[j];
            short4 o;
            o.x = f2bf(v.x); o.y = f2bf(v.y); o.z = f2bf(v.z); o.w = f2bf(v.w);
            ((short4*)out)[j] = o;
        }
        return;
    }

    if (blk == 4096) {
        if (t < 192)
            ((float4*)qubias)[t] = (t < 96) ? ((const float4*)bq)[t] : ((const float4*)bu)[t - 96];
        return;
    }

    // weight transposes (444 tiles of 64x64)
    int b = blk - 4097;
    const float* in; short* out; int R, C, local;
    if (b < 36)       { in = Wq; out = WquT;          R = 384;  C = 384;  local = b; }
    else if (b < 60)  { in = Wk; out = WkT;           R = 256;  C = 384;  local = b - 36; }
    else if (b < 84)  { in = Wv; out = WvT;           R = 256;  C = 384;  local = b - 60; }
    else if (b < 120) { in = Wu; out = WquT + 147456; R = 384;  C = 384;  local = b - 84; }
    else if (b < 156) { in = Wn; out = WnT;           R = 384;  C = 384;  local = b - 120; }
    else if (b < 300) { in = W1; out = W1T;           R = 384;  C = 1536; local = b - 156; }
    else              { in = W2; out = W2T;           R = 1536; C = 384;  local = b - 300; }
    const int nbx = C >> 6;
    const int r0 = (local / nbx) * 64, c0 = (local % nbx) * 64;
    const int lr = t >> 6, lc = t & 63;
#pragma unroll
    for (int i = 0; i < 16; ++i) {
        int r = lr * 16 + i;
        tile[r][lc] = in[(long long)(r0 + r) * C + c0 + lc];
    }
    __syncthreads();
#pragma unroll
    for (int i = 0; i < 16; ++i) {
        int r = lr * 16 + i;
        out[(long long)(c0 + r) * R + r0 + lc] = f2bf(tile[lc][r]);
    }
}

// blended dual softmax over rows of length 2048
__global__ __launch_bounds__(256) void softmax_blend(
    const short* __restrict__ attb, const short* __restrict__ mixb,
    const float* __restrict__ a1p,
    float* __restrict__ outF, short* __restrict__ outB)
{
    const int S = 2048;
    const long long row = blockIdx.x;
    const short* ar = attb + row * S;
    const short* mr = mixb + row * S;
    const int t = threadIdx.x;
    const int wave = t >> 6;

    bf16x8 a8 = *(const bf16x8*)&ar[t * 8];
    bf16x8 m8 = *(const bf16x8*)&mr[t * 8];
    float av[8], mv[8];
#pragma unroll
    for (int i = 0; i < 8; ++i) { av[i] = bf2f(a8[i]); mv[i] = bf2f(m8[i]); }

    float amax = av[0], mmax = mv[0];
#pragma unroll
    for (int i = 1; i < 8; ++i) { amax = fmaxf(amax, av[i]); mmax = fmaxf(mmax, mv[i]); }
#pragma unroll
    for (int o = 32; o; o >>= 1) {
        amax = fmaxf(amax, __shfl_xor(amax, o));
        mmax = fmaxf(mmax, __shfl_xor(mmax, o));
    }
    __shared__ float red[2][4];
    if ((t & 63) == 0) { red[0][wave] = amax; red[1][wave] = mmax; }
    __syncthreads();
    amax = fmaxf(fmaxf(red[0][0], red[0][1]), fmaxf(red[0][2], red[0][3]));
    mmax = fmaxf(fmaxf(red[1][0], red[1][1]), fmaxf(red[1][2], red[1][3]));

    float asum = 0.f, msum = 0.f;
#pragma unroll
    for (int i = 0; i < 8; ++i) {
        av[i] = __expf(av[i] - amax); asum += av[i];
        mv[i] = __expf(mv[i] - mmax); msum += mv[i];
    }
#pragma unroll
    for (int o = 32; o; o >>= 1) {
        asum += __shfl_xor(asum, o);
        msum += __shfl_xor(msum, o);
    }
    __shared__ float red2[2][4];
    if ((t & 63) == 0) { red2[0][wave] = asum; red2[1][wave] = msum; }
    __syncthreads();
    asum = red2[0][0] + red2[0][1] + red2[0][2] + red2[0][3];
    msum = red2[1][0] + red2[1][1] + red2[1][2] + red2[1][3];

    const float a1 = a1p[0];
    const float wm = a1 / msum;
    const float wa = (1.0f - a1) / asum;

    float o0[8];
    bf16x8 ob;
#pragma unroll
    for (int i = 0; i < 8; ++i) {
        float s = wm * mv[i] + wa * av[i];
        o0[i] = s;
        ob[i] = f2bf(s);
    }
    float4 f0, f1;
    f0.x = o0[0]; f0.y = o0[1]; f0.z = o0[2]; f0.w = o0[3];
    f1.x = o0[4]; f1.y = o0[5]; f1.z = o0[6]; f1.w = o0[7];
    *(float4*)&outF[row * S + t * 8] = f0;
    *(float4*)&outF[row * S + t * 8 + 4] = f1;
    *(bf16x8*)&outB[row * S + t * 8] = ob;
}

// LayerNorm over D=384 of (X + Y [+ Y2]); X fp32 or bf16 (XBF).
template<int WRITE_F, int WRITE_BF, int TWO_Y, int XBF>
__global__ __launch_bounds__(256) void ln_kernel(
    const void* __restrict__ Xv, const float* __restrict__ Yr,
    const float* __restrict__ Y2,
    const float* __restrict__ g, const float* __restrict__ be,
    float* __restrict__ outF, short* __restrict__ outB)
{
    const int Dm = 384;
    const int wave = threadIdx.x >> 6, lane = threadIdx.x & 63;
    const long long row = (long long)blockIdx.x * 4 + wave;
    const float* y = Yr + row * Dm;
    const float* y2 = TWO_Y ? (Y2 + row * Dm) : nullptr;
    float h[6];
    float s = 0.f, s2 = 0.f;
#pragma unroll
    for (int j = 0; j < 6; ++j) {
        int c = j * 64 + lane;
        float xv;
        if (XBF) xv = bf2f(((const short*)Xv)[row * Dm + c]);
        else     xv = ((const float*)Xv)[row * Dm + c];
        h[j] = xv + y[c];
        if (TWO_Y) h[j] += y2[c];
        s += h[j]; s2 += h[j] * h[j];
    }
#pragma unroll
    for (int o = 32; o; o >>= 1) { s += __shfl_xor(s, o); s2 += __shfl_xor(s2, o); }
    const float mean = s * (1.0f / 384.0f);
    const float var = s2 * (1.0f / 384.0f) - mean * mean;
    const float rstd = rsqrtf(var + 1e-5f);
#pragma unroll
    for (int j = 0; j < 6; ++j) {
        int c = j * 64 + lane;
        float v = (h[j] - mean) * rstd * g[c] + be[c];
        if (WRITE_F) outF[row * Dm + c] = v;
        if (WRITE_BF) outB[row * Dm + c] = f2bf(v);
    }
}

extern "C" void kernel_launch(void* const* d_in, const int* in_sizes, int n_in,
                              void* d_out, int out_size, void* d_ws, size_t ws_size,
                              hipStream_t stream) {
    const float* tgt     = (const float*)d_in[0];
    const float* memory  = (const float*)d_in[1];
    const float* a1      = (const float*)d_in[2];
    const float* score_c = (const float*)d_in[3];
    const float* out_c   = (const float*)d_in[4];
    const float* Wq = (const float*)d_in[5];  const float* bq = (const float*)d_in[6];
    const float* Wk = (const float*)d_in[7];  const float* bk = (const float*)d_in[8];
    const float* Wv = (const float*)d_in[9];  const float* bv = (const float*)d_in[10];
    const float* Wu = (const float*)d_in[11]; const float* bu = (const float*)d_in[12];
    const float* Wn = (const float*)d_in[13]; const float* bn = (const float*)d_in[14];
    const float* W1 = (const float*)d_in[15]; const float* b1 = (const float*)d_in[16];
    const float* W2 = (const float*)d_in[17]; const float* b2 = (const float*)d_in[18];
    const float* g1 = (const float*)d_in[19]; const float* be1 = (const float*)d_in[20];
    const float* g2 = (const float*)d_in[21]; const float* be2 = (const float*)d_in[22];

    const long long BT = 16384;            // B*T
    const long long S2 = 2048LL * 2048;    // per-batch score matrix elems
    const long long PB = 2048LL * 384;     // per-batch [2048,384] panel elems
    char* ws = (char*)d_ws;
    size_t off = 0;
    auto A_ = [&](size_t b) { size_t r = off; off += (b + 255) & ~(size_t)255; return r; };

    const size_t oTgtB  = A_(BT * 384 * 2);
    const size_t oMemB  = A_(BT * 256 * 2);
    const size_t oOutcB = A_(BT * 384 * 2);
    const size_t oWquT  = A_(768 * 384 * 2);
    const size_t oWnT   = A_(384 * 384 * 2);
    const size_t oWkT   = A_(384 * 256 * 2);
    const size_t oWvT   = A_(384 * 256 * 2);
    const size_t oW1T   = A_(1536 * 384 * 2);
    const size_t oW2T   = A_(384 * 1536 * 2);
    const size_t oQUb   = A_(768 * 4);
    const size_t oQU    = A_(16 * PB * 2);  // qu packed [16384, 768]
    const size_t oKP    = A_(16 * PB * 2);  // k (0-7), Pt (8-15)
    const size_t oVT    = A_(8LL * 384 * 2048 * 2);
    const size_t oJ     = A_(8 * S2 * 2);   // score_bf (blend output)
    const size_t oKr    = A_(8 * S2 * 2);   // z0|z1 fp32 halves
    const size_t oAM    = A_(16 * S2 * 2);  // knoT + ptH early; att|mixed; later h_bf / ff_f
    const size_t oXB    = A_(BT * 384 * 2);

    short* tgt_bf  = (short*)(ws + oTgtB);
    short* mem_bf  = (short*)(ws + oMemB);
    short* outc_bf = (short*)(ws + oOutcB);
    short* WquT = (short*)(ws + oWquT);
    short* WnT  = (short*)(ws + oWnT);
    short* WkT  = (short*)(ws + oWkT);
    short* WvT  = (short*)(ws + oWvT);
    short* W1T  = (short*)(ws + oW1T);
    short* W2T  = (short*)(ws + oW2T);
    float* qu_bias = (float*)(ws + oQUb);
    short* qu_bf  = (short*)(ws + oQU);
    short* k_bf   = (short*)(ws + oKP);
    short* Pt_bf  = k_bf + 8 * PB;
    short* vT_bf  = (short*)(ws + oVT);
    short* score_bf = (short*)(ws + oJ);
    float* z0_f     = (float*)(ws + oKr);
    float* z1_f     = z0_f + 6291456;
    short* knoT_bf  = (short*)(ws + oAM);   // alias: dead before att written
    float* ptH_f    = (float*)(ws + oAM + 32LL * 1024 * 1024);  // Pt fp32 halves, dead before att
    short* att_bf   = (short*)(ws + oAM);
    short* mix_bf   = att_bf + 8 * S2;
    short* h_bf     = (short*)(ws + oAM);               // alias (att dead after blend)
    float* ff_f     = (float*)(ws + oAM + 8 * S2 * 2);  // alias (mixed dead after blend)
    short* x_bf = (short*)(ws + oXB);

    float* outMain = (float*)d_out;
    float* outScore = (float*)d_out + 6291456;   // B*T*D elements

    const float SC = 0.05103103630798288f;  // 1/sqrt(384)
    dim3 blk(256);

    // prologue: casts + bias concat + weight transposes
    prologue<<<4541, blk, 0, stream>>>(
        tgt, memory, out_c, bq, bu, tgt_bf, mem_bf, outc_bf, qu_bias,
        Wq, Wk, Wv, Wu, Wn, W1, W2, WquT, WkT, WvT, WnT, W1T, W2T);

    // qu (bx 0-5) + k (bx 6-8) projections in one launch
    gemm128rr<<<dim3(9, 128, 1), blk, 0, stream>>>(
        tgt_bf, WquT, qu_bf, qu_bias, 384, 384, 384, 768,
        mem_bf, WkT, k_bf, bk, 256, 256, 256, 384);
    // vT (z 0-7) + knoT (z 8-15) merged
    gemm128pz<<<dim3(16, 3, 16), blk, 0, stream>>>(
        WvT, mem_bf, vT_bf, bv, 256, 256, 256, 2048, 2048LL * 256, PB,
        WnT, outc_bf, knoT_bf, bn, 384, 384, 384, 2048, PB, PB);
    // Pt = score_c^T @ knoT^T, TN GEMM, K-split x2 (zhi) into fp32 halves
    gemmTN<<<dim3(3, 16, 16), blk, 0, stream>>>(
        score_c, knoT_bf, ptH_f, S2, PB, PB, 6291456);
    combine_bf<<<6144, blk, 0, stream>>>(ptH_f, 6291456, Pt_bf);
    // att (z 0-7: q x k) + mixed (z 8-15: unk x Pt), wide engine + staged epilogue
    gemmWide<1, 0, 0><<<dim3(8, 16, 16), blk, 0, stream>>>(
        qu_bf, k_bf, att_bf, nullptr, 384, 768, 384, 2048,
        2048LL * 768, PB, S2, 384, 8 * PB, 8 * S2, SC);
    // score = a1*softmax(mixed) + (1-a1)*softmax(att)
    softmax_blend<<<16384, blk, 0, stream>>>(att_bf, mix_bf, a1, outScore, score_bf);
    // z = score @ v, K split in two halves (z planes 8-15 do k in [1024,2048))
    gemm128r<0, 0, 0><<<dim3(3, 16, 16), blk, 0, stream>>>(
        score_bf, vT_bf, z0_f, nullptr, 1024, 2048, 2048, 384,
        S2, PB, PB, 1024, 1024, 6291456, 1.0f);
    // x = LN(tgt + z0 + z1) -> bf16 only
    ln_kernel<0, 1, 1, 0><<<4096, blk, 0, stream>>>(
        tgt, z0_f, z1_f, g1, be1, nullptr, x_bf);
    // FFN1
    gemm128r<1, 1, 1><<<dim3(12, 128, 1), blk, 0, stream>>>(
        x_bf, W1T, h_bf, b1, 384, 384, 384, 1536, 0, 0, 0, 0, 0, 0, 1.0f);
    // FFN2 (bias in GEMM)
    gemm128r<0, 1, 0><<<dim3(3, 128, 1), blk, 0, stream>>>(
        h_bf, W2T, ff_f, b2, 1536, 1536, 1536, 384, 0, 0, 0, 0, 0, 0, 1.0f);
    // out = LN(x + ff), x read as bf16
    ln_kernel<1, 0, 0, 1><<<4096, blk, 0, stream>>>(
        x_bf, ff_f, nullptr, g2, be2, outMain, nullptr);
}

// Round 18
// 425.634 us; speedup vs baseline: 1.0012x; 1.0012x over previous
//
#include <hip/hip_runtime.h>
#include <stdint.h>

typedef __attribute__((ext_vector_type(8))) short bf16x8;
typedef __attribute__((ext_vector_type(4))) short bf16x4;
typedef __attribute__((ext_vector_type(4))) float f32x4;

__device__ __forceinline__ short f2bf(float f) {
    union { float f; unsigned u; } v; v.f = f;
    unsigned r = v.u + 0x7fffu + ((v.u >> 16) & 1u);
    return (short)(r >> 16);
}
__device__ __forceinline__ float bf2f(short s) {
    union { unsigned u; float f; } v;
    v.u = ((unsigned)(unsigned short)s) << 16;
    return v.f;
}

__device__ __forceinline__ void gld16(const void* g, void* l) {
    auto gp = reinterpret_cast<const __attribute__((address_space(1))) unsigned int*>(
        reinterpret_cast<uintptr_t>(g));
    auto lp = reinterpret_cast<__attribute__((address_space(3))) unsigned int*>(
        reinterpret_cast<uintptr_t>(l));
    __builtin_amdgcn_global_load_lds(gp, lp, 16, 0, 0);
}

// ---------------------------------------------------------------------------
// gemmBig: 256x256 NT GEMM for att+mix. 512 threads, 8 waves (4 row x 2 col),
// wave-tile 64x128 (same per-wave geometry/swizzle as the verified 128x256
// engine). WHY: 128x256 tiles stage 11.4 B/kFLOP = exactly the L2->CU BW
// roofline (58 B/cyc vs 5120 FLOP/cyc) -> all schedules stuck ~21% MfmaUtil.
// 256x256 halves staging per FLOP (5.7 B/kFLOP) -> compute-bound.
// Ring-3 LDS (96 KB, 1 block/CU), stage distance 2, counted vmcnt(4)
// (4 loads/thread/tile). Batch addressing: z: A += (z&7)*sA + (z>>3)*dA etc.
// K%64==0, rows per plane = gy*256, cols = gx*256, nwg%8==0.
// ---------------------------------------------------------------------------
__global__ __launch_bounds__(512, 1) void gemmBig(
    const short* __restrict__ Ag, const short* __restrict__ Bg,
    short* __restrict__ Cg,
    int K, int lda, int ldb, int ldc,
    long long sA, long long sB, long long sC,
    long long dA, long long dB, long long dC, float scale)
{
    __shared__ short lds[3 * 16384];   // per buf: A[256][32] 8192 | B[256][32] 8192
    const int t = threadIdx.x;
    const int lane = t & 63;
    const int wave = t >> 6;
    const int wm = wave >> 1;          // 0..3  (64-row slice)
    const int wn = wave & 1;           // 0..1  (128-col slice)

    const int gx = gridDim.x, gy = gridDim.y;
    const int nwg = gx * gy * gridDim.z;
    int id = blockIdx.x + gx * (blockIdx.y + gy * blockIdx.z);
    id = (id & 7) * (nwg >> 3) + (id >> 3);
    const int bx = id % gx;
    const int by = (id / gx) % gy;
    const int bz = id / (gx * gy);
    const int zlo = bz & 7, zhi = bz >> 3;

    const long long row0 = (long long)by * 256;
    const long long col0 = (long long)bx * 256;
    const int NT = K >> 5;

    // staging: thread t covers rows (t>>2) and (t>>2)+128, col-seg (t&3),
    // source col pre-swizzled with the involution (function of row bits 0-3,
    // invariant under row+128) so swizzled reads see correct data.
    const int gk = ((t & 3) ^ ((t >> 2) & 3) ^ ((t >> 4) & 3)) * 8;
    const short* Asrc = Ag + zlo * sA + zhi * dA + (row0 + (t >> 2)) * (long long)lda + gk;
    const short* Bsrc = Bg + zlo * sB + zhi * dB + (col0 + (t >> 2)) * (long long)ldb + gk;

    const int frow = lane & 15;
    const int fcol = ((lane >> 4) ^ (frow & 3) ^ ((frow >> 2) & 3)) * 8;

    f32x4 acc[4][8] = {};

#define STG(BUF, KC) do { \
        gld16(Asrc + (KC), &lds[(BUF) * 16384 + t * 8]); \
        gld16(Asrc + (KC) + 128LL * lda, &lds[(BUF) * 16384 + 4096 + t * 8]); \
        gld16(Bsrc + (KC), &lds[(BUF) * 16384 + 8192 + t * 8]); \
        gld16(Bsrc + (KC) + 128LL * ldb, &lds[(BUF) * 16384 + 12288 + t * 8]); } while (0)

    STG(0, 0);
    STG(1, 32);
    asm volatile("s_waitcnt vmcnt(4)\ns_barrier" ::: "memory");

    for (int kt = 0; kt < NT; ++kt) {
        const int rb = (kt % 3) * 16384;
        bf16x8 av[4], bv[8];
#pragma unroll
        for (int m = 0; m < 4; ++m)
            av[m] = *(const bf16x8*)&lds[rb + (wm * 64 + m * 16 + frow) * 32 + fcol];
#pragma unroll
        for (int n = 0; n < 8; ++n)
            bv[n] = *(const bf16x8*)&lds[rb + 8192 + (wn * 128 + n * 16 + frow) * 32 + fcol];
        if (kt + 2 < NT) STG((kt + 2) % 3, (long long)(kt + 2) * 32);
        __builtin_amdgcn_s_setprio(1);
#pragma unroll
        for (int m = 0; m < 4; ++m)
#pragma unroll
            for (int n = 0; n < 8; ++n)
                acc[m][n] = __builtin_amdgcn_mfma_f32_16x16x32_bf16(av[m], bv[n], acc[m][n], 0, 0, 0);
        __builtin_amdgcn_s_setprio(0);
        if (kt + 1 < NT) {
            if (kt + 2 < NT) asm volatile("s_waitcnt vmcnt(4)\ns_barrier" ::: "memory");
            else             asm volatile("s_waitcnt vmcnt(0)\ns_barrier" ::: "memory");
        }
    }
#undef STG

    const int crow = (lane >> 4) * 4;
    const int ccol = lane & 15;
    const long long cz = zlo * sC + zhi * dC;
#pragma unroll
    for (int m = 0; m < 4; ++m)
#pragma unroll
        for (int n = 0; n < 8; ++n)
#pragma unroll
            for (int i = 0; i < 4; ++i) {
                long long r = row0 + wm * 64 + m * 16 + crow + i;
                long long c = col0 + wn * 128 + n * 16 + ccol;
                Cg[cz + r * (long long)ldc + c] = f2bf(acc[m][n][i] * scale);
            }
}

// ---------------------------------------------------------------------------
// gemmTN: Pt_half[s,d] = sum_{c in half} score_c[c,s] * knoT[d,c].
// (verified round 16) K-split x2 via zhi, fp32 partials, grid (3,16,16).
// ---------------------------------------------------------------------------
__global__ __launch_bounds__(256, 3) void gemmTN(
    const float* __restrict__ Ag, const short* __restrict__ Bg,
    float* __restrict__ Cg,
    long long sA, long long sB, long long sC, long long dC)
{
    __shared__ short lds[2 * 8256];   // per buf: A 4160 (8 quads x 520) | B 4096
    const int t = threadIdx.x;
    const int lane = t & 63;
    const int wave = t >> 6;
    const int wm = wave >> 1, wn = wave & 1;

    const int nwg = 3 * 16 * 16;
    int id = blockIdx.x + 3 * (blockIdx.y + 16 * blockIdx.z);
    id = (id & 7) * (nwg >> 3) + (id >> 3);
    const int bx = id % 3;
    const int by = (id / 3) % 16;
    const int bzz = id / 48;
    const int zlo = bzz & 7, zhi = bzz >> 3;

    const long long s0 = (long long)by * 128;
    const int d0 = bx * 128;
    const int q = t >> 5, kk = t & 31;
    const float* Asrc = Ag + zlo * sA + (long long)zhi * 1024 * 2048
                        + (long long)(q * 4) * 2048 + s0 + kk * 4;

    const int gk = ((t & 3) ^ ((t >> 2) & 3) ^ ((t >> 4) & 3)) * 8;
    const short* Bsrc = Bg + zlo * sB + zhi * 1024 + (d0 + (t >> 2)) * 2048LL + gk;

    const int frow = lane & 15;
    const int g = lane >> 4;
    const int fcol = (g ^ (frow & 3) ^ ((frow >> 2) & 3)) * 8;

    f32x4 acc[4][4] = {};
    f32x4 ar[4];

#define STAGE_B(BUF, KC) do { \
        gld16(Bsrc + (KC), &lds[(BUF) + 4160 + t * 8]); \
        gld16(Bsrc + (KC) + 64LL * 2048, &lds[(BUF) + 4160 + 2048 + t * 8]); } while (0)

#define WRITE_A(BUF) do { \
        short tmp[16]; \
        _Pragma("unroll") \
        for (int i = 0; i < 16; ++i) tmp[i] = f2bf(ar[i & 3][i >> 2]); \
        short* dst = &lds[(BUF) + q * 520 + kk * 16]; \
        *(bf16x8*)dst = *(bf16x8*)&tmp[0]; \
        *(bf16x8*)(dst + 8) = *(bf16x8*)&tmp[8]; } while (0)

#pragma unroll
    for (int r = 0; r < 4; ++r) ar[r] = *(const f32x4*)&Asrc[(long long)r * 2048];
    STAGE_B(0, 0);
    WRITE_A(0);
    asm volatile("s_waitcnt vmcnt(0) lgkmcnt(0)\ns_barrier" ::: "memory");
#pragma unroll
    for (int r = 0; r < 4; ++r) ar[r] = *(const f32x4*)&Asrc[65536LL + r * 2048];

    const int NT = 32;   // K-half = 1024, BK = 32
    for (int kt = 0; kt < NT; ++kt) {
        const int rb = (kt & 1) * 8256;
        const int wb = ((kt + 1) & 1) * 8256;

        bf16x8 av[4], bv[4];
#pragma unroll
        for (int m = 0; m < 4; ++m) {
            const int sl = (wm * 64 + m * 16 + frow) * 4;
            bf16x4 lo = *(const bf16x4*)&lds[rb + 1040 * g + sl];
            bf16x4 hi = *(const bf16x4*)&lds[rb + 1040 * g + 520 + sl];
            av[m] = __builtin_shufflevector(lo, hi, 0, 1, 2, 3, 4, 5, 6, 7);
        }
#pragma unroll
        for (int n = 0; n < 4; ++n)
            bv[n] = *(const bf16x8*)&lds[rb + 4160 + (wn * 64 + n * 16 + frow) * 32 + fcol];

        if (kt + 1 < NT) {
            STAGE_B(wb, (long long)(kt + 1) * 32);
            WRITE_A(wb);
        }
#pragma unroll
        for (int m = 0; m < 4; ++m)
#pragma unroll
            for (int n = 0; n < 4; ++n)
                acc[m][n] = __builtin_amdgcn_mfma_f32_16x16x32_bf16(av[m], bv[n], acc[m][n], 0, 0, 0);
        if (kt + 1 < NT) {
            asm volatile("s_waitcnt vmcnt(0) lgkmcnt(0)\ns_barrier" ::: "memory");
            if (kt + 2 < NT) {
#pragma unroll
                for (int r = 0; r < 4; ++r)
                    ar[r] = *(const f32x4*)&Asrc[(long long)(kt + 2) * 65536 + r * 2048];
            }
        }
    }
#undef STAGE_B
#undef WRITE_A

    const int crow = (lane >> 4) * 4;
    const int ccol = lane & 15;
    const long long cz = zlo * sC + zhi * dC;
#pragma unroll
    for (int m = 0; m < 4; ++m)
#pragma unroll
        for (int n = 0; n < 4; ++n)
#pragma unroll
            for (int i = 0; i < 4; ++i) {
                long long r = s0 + wm * 64 + m * 16 + crow + i;
                long long c = d0 + wn * 64 + n * 16 + ccol;
                Cg[cz + r * 384 + c] = acc[m][n][i];
            }
}

// combine K-split fp32 halves -> bf16: out[i] = bf16(p[i] + p[i+half])
__global__ __launch_bounds__(256) void combine_bf(
    const float* __restrict__ p, long long half, short* __restrict__ out)
{
    long long i = ((long long)blockIdx.x * 256 + threadIdx.x) * 4;
    if (i + 3 < half) {
        float4 a = *(const float4*)&p[i];
        float4 b = *(const float4*)&p[i + half];
        short4 o;
        o.x = f2bf(a.x + b.x); o.y = f2bf(a.y + b.y);
        o.z = f2bf(a.z + b.z); o.w = f2bf(a.w + b.w);
        *(short4*)&out[i] = o;
    }
}

// ---------------------------------------------------------------------------
// gemm128r: 128x128 NT GEMM, BK=32, ring-3 (verified round 7).
// ---------------------------------------------------------------------------
template<int OUTBF, int BIASMODE /*0 none,1 col,2 row*/, int DORELU>
__global__ __launch_bounds__(256, 3) void gemm128r(
    const short* __restrict__ Ag, const short* __restrict__ Bg,
    void* __restrict__ Cg, const float* __restrict__ bias,
    int K, int lda, int ldb, int ldc,
    long long sA, long long sB, long long sC,
    long long dA, long long dB, long long dC, float scale)
{
    __shared__ short lds[3 * 8192];
    const int t = threadIdx.x;
    const int lane = t & 63;
    const int wave = t >> 6;
    const int wm = wave >> 1, wn = wave & 1;

    const int gx = gridDim.x, gy = gridDim.y;
    const int nwg = gx * gy * gridDim.z;
    int id = blockIdx.x + gx * (blockIdx.y + gy * blockIdx.z);
    id = (id & 7) * (nwg >> 3) + (id >> 3);
    const int bx = id % gx;
    const int by = (id / gx) % gy;
    const int bz = id / (gx * gy);
    const int zlo = bz & 7, zhi = bz >> 3;

    const long long row0 = (long long)by * 128;
    const long long col0 = (long long)bx * 128;
    const int NT = K >> 5;

    const int gk = ((t & 3) ^ ((t >> 2) & 3) ^ ((t >> 4) & 3)) * 8;
    const short* Asrc = Ag + zlo * sA + zhi * dA + (row0 + (t >> 2)) * (long long)lda + gk;
    const short* Bsrc = Bg + zlo * sB + zhi * dB + (col0 + (t >> 2)) * (long long)ldb + gk;

    const int frow = lane & 15;
    const int fcol = ((lane >> 4) ^ (frow & 3) ^ ((frow >> 2) & 3)) * 8;

    f32x4 acc[4][4] = {};

#define STG(BUF, KC) do { \
        gld16(Asrc + (KC), &lds[(BUF) * 8192 + t * 8]); \
        gld16(Asrc + (KC) + 64LL * lda, &lds[(BUF) * 8192 + 2048 + t * 8]); \
        gld16(Bsrc + (KC), &lds[(BUF) * 8192 + 4096 + t * 8]); \
        gld16(Bsrc + (KC) + 64LL * ldb, &lds[(BUF) * 8192 + 6144 + t * 8]); } while (0)

    STG(0, 0);
    STG(1, 32);
    asm volatile("s_waitcnt vmcnt(4)\ns_barrier" ::: "memory");

    for (int kt = 0; kt < NT; ++kt) {
        const int rb = (kt % 3) * 8192;
        bf16x8 av[4], bv[4];
#pragma unroll
        for (int m = 0; m < 4; ++m)
            av[m] = *(const bf16x8*)&lds[rb + (wm * 64 + m * 16 + frow) * 32 + fcol];
#pragma unroll
        for (int n = 0; n < 4; ++n)
            bv[n] = *(const bf16x8*)&lds[rb + 4096 + (wn * 64 + n * 16 + frow) * 32 + fcol];
        if (kt + 2 < NT) STG((kt + 2) % 3, (long long)(kt + 2) * 32);
        __builtin_amdgcn_s_setprio(1);
#pragma unroll
        for (int m = 0; m < 4; ++m)
#pragma unroll
            for (int n = 0; n < 4; ++n)
                acc[m][n] = __builtin_amdgcn_mfma_f32_16x16x32_bf16(av[m], bv[n], acc[m][n], 0, 0, 0);
        __builtin_amdgcn_s_setprio(0);
        if (kt + 1 < NT) {
            if (kt + 2 < NT) asm volatile("s_waitcnt vmcnt(4)\ns_barrier" ::: "memory");
            else             asm volatile("s_waitcnt vmcnt(0)\ns_barrier" ::: "memory");
        }
    }
#undef STG

    const int crow = (lane >> 4) * 4;
    const int ccol = lane & 15;
    const long long cz = zlo * sC + zhi * dC;
#pragma unroll
    for (int m = 0; m < 4; ++m)
#pragma unroll
        for (int n = 0; n < 4; ++n)
#pragma unroll
            for (int i = 0; i < 4; ++i) {
                long long r = row0 + wm * 64 + m * 16 + crow + i;
                long long c = col0 + wn * 64 + n * 16 + ccol;
                float v = acc[m][n][i] * scale;
                if (BIASMODE == 1) v += bias[c];
                if (BIASMODE == 2) v += bias[r];
                if (DORELU) v = fmaxf(v, 0.0f);
                long long idx = cz + r * (long long)ldc + c;
                if (OUTBF) ((short*)Cg)[idx] = f2bf(v);
                else ((float*)Cg)[idx] = v;
            }
}

// ---------------------------------------------------------------------------
// gemm128rr: bx-keyed dual 128r (qu: bx<6, k: bx>=6). Grid (9,128,1).
// ---------------------------------------------------------------------------
__global__ __launch_bounds__(256, 3) void gemm128rr(
    const short* __restrict__ A1, const short* __restrict__ B1,
    short* __restrict__ C1, const float* __restrict__ bias1,
    int K1, int lda1, int ldb1, int ldc1,
    const short* __restrict__ A2, const short* __restrict__ B2,
    short* __restrict__ C2, const float* __restrict__ bias2,
    int K2, int lda2, int ldb2, int ldc2)
{
    __shared__ short lds[3 * 8192];
    const int t = threadIdx.x;
    const int lane = t & 63;
    const int wave = t >> 6;
    const int wm = wave >> 1, wn = wave & 1;

    const int gx = gridDim.x, gy = gridDim.y;
    const int nwg = gx * gy;
    int id = blockIdx.x + gx * blockIdx.y;
    id = (id & 7) * (nwg >> 3) + (id >> 3);
    const int bx = id % gx;
    const int by = id / gx;

    const bool sel = bx >= 6;
    const int bxx = sel ? bx - 6 : bx;
    const short* Ag = sel ? A2 : A1;
    const short* Bg = sel ? B2 : B1;
    short* Cg = sel ? C2 : C1;
    const float* bias = sel ? bias2 : bias1;
    const int K = sel ? K2 : K1;
    const int lda = sel ? lda2 : lda1;
    const int ldb = sel ? ldb2 : ldb1;
    const int ldc = sel ? ldc2 : ldc1;

    const long long row0 = (long long)by * 128;
    const long long col0 = (long long)bxx * 128;
    const int NT = K >> 5;

    const int gk = ((t & 3) ^ ((t >> 2) & 3) ^ ((t >> 4) & 3)) * 8;
    const short* Asrc = Ag + (row0 + (t >> 2)) * (long long)lda + gk;
    const short* Bsrc = Bg + (col0 + (t >> 2)) * (long long)ldb + gk;

    const int frow = lane & 15;
    const int fcol = ((lane >> 4) ^ (frow & 3) ^ ((frow >> 2) & 3)) * 8;

    f32x4 acc[4][4] = {};

#define STG(BUF, KC) do { \
        gld16(Asrc + (KC), &lds[(BUF) * 8192 + t * 8]); \
        gld16(Asrc + (KC) + 64LL * lda, &lds[(BUF) * 8192 + 2048 + t * 8]); \
        gld16(Bsrc + (KC), &lds[(BUF) * 8192 + 4096 + t * 8]); \
        gld16(Bsrc + (KC) + 64LL * ldb, &lds[(BUF) * 8192 + 6144 + t * 8]); } while (0)

    STG(0, 0);
    STG(1, 32);
    asm volatile("s_waitcnt vmcnt(4)\ns_barrier" ::: "memory");

    for (int kt = 0; kt < NT; ++kt) {
        const int rb = (kt % 3) * 8192;
        bf16x8 av[4], bv[4];
#pragma unroll
        for (int m = 0; m < 4; ++m)
            av[m] = *(const bf16x8*)&lds[rb + (wm * 64 + m * 16 + frow) * 32 + fcol];
#pragma unroll
        for (int n = 0; n < 4; ++n)
            bv[n] = *(const bf16x8*)&lds[rb + 4096 + (wn * 64 + n * 16 + frow) * 32 + fcol];
        if (kt + 2 < NT) STG((kt + 2) % 3, (long long)(kt + 2) * 32);
        __builtin_amdgcn_s_setprio(1);
#pragma unroll
        for (int m = 0; m < 4; ++m)
#pragma unroll
            for (int n = 0; n < 4; ++n)
                acc[m][n] = __builtin_amdgcn_mfma_f32_16x16x32_bf16(av[m], bv[n], acc[m][n], 0, 0, 0);
        __builtin_amdgcn_s_setprio(0);
        if (kt + 1 < NT) {
            if (kt + 2 < NT) asm volatile("s_waitcnt vmcnt(4)\ns_barrier" ::: "memory");
            else             asm volatile("s_waitcnt vmcnt(0)\ns_barrier" ::: "memory");
        }
    }
#undef STG

    const int crow = (lane >> 4) * 4;
    const int ccol = lane & 15;
#pragma unroll
    for (int m = 0; m < 4; ++m)
#pragma unroll
        for (int n = 0; n < 4; ++n)
#pragma unroll
            for (int i = 0; i < 4; ++i) {
                long long r = row0 + wm * 64 + m * 16 + crow + i;
                long long c = col0 + wn * 64 + n * 16 + ccol;
                float v = acc[m][n][i] + bias[c];
                Cg[r * (long long)ldc + c] = f2bf(v);
            }
}

// ---------------------------------------------------------------------------
// gemm128pz: dual-parameter 2-phase engine (verified round 6), z<8 -> vT,
// z>=8 -> knoT. Both: C = A @ B^T + rowbias, A = weight.
// ---------------------------------------------------------------------------
#define RD_A(RB, M, KS) (*(const bf16x8*)&lds[(RB) + (wm * 64 + (M) * 16 + frow) * 64 + \
        ((((KS) << 2) | fq) ^ (frow & 7)) * 8])
#define RD_B(RB, Nn, KS) (*(const bf16x8*)&lds[(RB) + 8192 + (wn * 64 + (Nn) * 16 + frow) * 64 + \
        ((((KS) << 2) | fq) ^ (frow & 7)) * 8])

__global__ __launch_bounds__(256, 2) void gemm128pz(
    const short* __restrict__ A1, const short* __restrict__ B1, short* __restrict__ C1,
    const float* __restrict__ bias1, int K1, int lda1, int ldb1, int ldc1,
    long long sB1, long long sC1,
    const short* __restrict__ A2, const short* __restrict__ B2, short* __restrict__ C2,
    const float* __restrict__ bias2, int K2, int lda2, int ldb2, int ldc2,
    long long sB2, long long sC2)
{
    __shared__ short lds[2 * 16384];
    const int t = threadIdx.x;
    const int lane = t & 63;
    const int wave = t >> 6;
    const int wm = wave >> 1, wn = wave & 1;

    const int gx = gridDim.x, gy = gridDim.y;
    const int nwg = gx * gy * gridDim.z;
    int id = blockIdx.x + gx * (blockIdx.y + gy * blockIdx.z);
    id = (id & 7) * (nwg >> 3) + (id >> 3);
    const int bx = id % gx;
    const int by = (id / gx) % gy;
    const int bz = id / (gx * gy);

    const bool sel = bz >= 8;
    const int zz = bz & 7;
    const short* Ag = sel ? A2 : A1;
    const short* Bg = sel ? B2 : B1;
    short* Cg = sel ? C2 : C1;
    const float* bias = sel ? bias2 : bias1;
    const int K = sel ? K2 : K1;
    const int lda = sel ? lda2 : lda1;
    const int ldb = sel ? ldb2 : ldb1;
    const int ldc = sel ? ldc2 : ldc1;
    const long long sB = sel ? sB2 : sB1;
    const long long sC = sel ? sC2 : sC1;

    const long long row0 = (long long)by * 128;
    const long long col0 = (long long)bx * 128;
    const int NT = K >> 6;

    const int srow = t >> 3;
    const int gk = ((t & 7) ^ (srow & 7)) * 8;
    const short* Asrc = Ag + (row0 + srow) * (long long)lda + gk;
    const short* Bsrc = Bg + (long long)zz * sB + (col0 + srow) * (long long)ldb + gk;

    const int frow = lane & 15;
    const int fq = lane >> 4;

    f32x4 acc[4][4] = {};

#define STAGE_A(WB, KC) do { _Pragma("unroll") \
        for (int r = 0; r < 4; ++r) \
            gld16(Asrc + (KC) + (long long)r * 32 * lda, &lds[(WB) + t * 8 + r * 2048]); } while (0)
#define STAGE_B(WB, KC) do { _Pragma("unroll") \
        for (int r = 0; r < 4; ++r) \
            gld16(Bsrc + (KC) + (long long)r * 32 * ldb, &lds[(WB) + 8192 + t * 8 + r * 2048]); } while (0)

    STAGE_A(0, 0);
    STAGE_B(0, 0);
    asm volatile("s_waitcnt vmcnt(0)\ns_barrier" ::: "memory");

    for (int kt = 0; kt < NT; ++kt) {
        const int rb = (kt & 1) << 14;
        const int wb = ((kt + 1) & 1) << 14;
        const bool st = (kt + 1) < NT;
        const long long kc = (long long)(kt + 1) << 6;

        bf16x8 av[4], bv[4];

#pragma unroll
        for (int m = 0; m < 4; ++m) av[m] = RD_A(rb, m, 0);
#pragma unroll
        for (int n = 0; n < 4; ++n) bv[n] = RD_B(rb, n, 0);
        if (st) STAGE_A(wb, kc);
        asm volatile("s_barrier" ::: "memory");
        __builtin_amdgcn_s_setprio(1);
#pragma unroll
        for (int m = 0; m < 4; ++m)
#pragma unroll
            for (int n = 0; n < 4; ++n)
                acc[m][n] = __builtin_amdgcn_mfma_f32_16x16x32_bf16(av[m], bv[n], acc[m][n], 0, 0, 0);
        __builtin_amdgcn_s_setprio(0);
        asm volatile("s_barrier" ::: "memory");

#pragma unroll
        for (int m = 0; m < 4; ++m) av[m] = RD_A(rb, m, 1);
#pragma unroll
        for (int n = 0; n < 4; ++n) bv[n] = RD_B(rb, n, 1);
        if (st) STAGE_B(wb, kc);
        asm volatile("s_barrier" ::: "memory");
        __builtin_amdgcn_s_setprio(1);
#pragma unroll
        for (int m = 0; m < 4; ++m)
#pragma unroll
            for (int n = 0; n < 4; ++n)
                acc[m][n] = __builtin_amdgcn_mfma_f32_16x16x32_bf16(av[m], bv[n], acc[m][n], 0, 0, 0);
        __builtin_amdgcn_s_setprio(0);
        if (st) asm volatile("s_waitcnt vmcnt(0)\ns_barrier" ::: "memory");
        else    asm volatile("s_barrier" ::: "memory");
    }
#undef STAGE_A
#undef STAGE_B

    const int crow = (lane >> 4) * 4;
    const int ccol = lane & 15;
    const long long cz = (long long)zz * sC;
#pragma unroll
    for (int m = 0; m < 4; ++m)
#pragma unroll
        for (int n = 0; n < 4; ++n)
#pragma unroll
            for (int i = 0; i < 4; ++i) {
                long long r = row0 + wm * 64 + m * 16 + crow + i;
                long long c = col0 + wn * 64 + n * 16 + ccol;
                float v = acc[m][n][i] + bias[r];
                Cg[cz + r * (long long)ldc + c] = f2bf(v);
            }
}
#undef RD_A
#undef RD_B

// ---------------------------------------------------------------------------
// prologue v3: [0,4096) cast 4xfloat4/thread | 4096 bias | [4097,4541) weight
// transposes (64x64). score_c transpose ELIMINATED (gemmTN reads it directly).
// ---------------------------------------------------------------------------
__global__ __launch_bounds__(256) void prologue(
    const float* __restrict__ tgt, const float* __restrict__ mem, const float* __restrict__ outc,
    const float* __restrict__ bq, const float* __restrict__ bu,
    short* __restrict__ tgtb, short* __restrict__ memb, short* __restrict__ outcb,
    float* __restrict__ qubias,
    const float* __restrict__ Wq, const float* __restrict__ Wk, const float* __restrict__ Wv,
    const float* __restrict__ Wu, const float* __restrict__ Wn,
    const float* __restrict__ W1, const float* __restrict__ W2,
    short* __restrict__ WquT, short* __restrict__ WkT, short* __restrict__ WvT,
    short* __restrict__ WnT, short* __restrict__ W1T, short* __restrict__ W2T)
{
    __shared__ float tile[64][65];
    const int blk = blockIdx.x;
    const int t = threadIdx.x;

    if (blk < 4096) {
        const long long R1 = 1572864;
        const long long R2 = R1 + 1048576;
        const long long base = (long long)blk * 1024 + t;
#pragma unroll
        for (int s = 0; s < 4; ++s) {
            long long i = base + s * 256;
            const float* in; short* out; long long j;
            if (i < R1) { in = tgt; out = tgtb; j = i; }
            else if (i < R2) { in = mem; out = memb; j = i - R1; }
            else { in = outc; out = outcb; j = i - R2; }
            float4 v = ((const float4*)in)[j];
            short4 o;
            o.x = f2bf(v.x); o.y = f2bf(v.y); o.z = f2bf(v.z); o.w = f2bf(v.w);
            ((short4*)out)[j] = o;
        }
        return;
    }

    if (blk == 4096) {
        if (t < 192)
            ((float4*)qubias)[t] = (t < 96) ? ((const float4*)bq)[t] : ((const float4*)bu)[t - 96];
        return;
    }

    // weight transposes (444 tiles of 64x64)
    int b = blk - 4097;
    const float* in; short* out; int R, C, local;
    if (b < 36)       { in = Wq; out = WquT;          R = 384;  C = 384;  local = b; }
    else if (b < 60)  { in = Wk; out = WkT;           R = 256;  C = 384;  local = b - 36; }
    else if (b < 84)  { in = Wv; out = WvT;           R = 256;  C = 384;  local = b - 60; }
    else if (b < 120) { in = Wu; out = WquT + 147456; R = 384;  C = 384;  local = b - 84; }
    else if (b < 156) { in = Wn; out = WnT;           R = 384;  C = 384;  local = b - 120; }
    else if (b < 300) { in = W1; out = W1T;           R = 384;  C = 1536; local = b - 156; }
    else              { in = W2; out = W2T;           R = 1536; C = 384;  local = b - 300; }
    const int nbx = C >> 6;
    const int r0 = (local / nbx) * 64, c0 = (local % nbx) * 64;
    const int lr = t >> 6, lc = t & 63;
#pragma unroll
    for (int i = 0; i < 16; ++i) {
        int r = lr * 16 + i;
        tile[r][lc] = in[(long long)(r0 + r) * C + c0 + lc];
    }
    __syncthreads();
#pragma unroll
    for (int i = 0; i < 16; ++i) {
        int r = lr * 16 + i;
        out[(long long)(c0 + r) * R + r0 + lc] = f2bf(tile[lc][r]);
    }
}

// blended dual softmax over rows of length 2048
__global__ __launch_bounds__(256) void softmax_blend(
    const short* __restrict__ attb, const short* __restrict__ mixb,
    const float* __restrict__ a1p,
    float* __restrict__ outF, short* __restrict__ outB)
{
    const int S = 2048;
    const long long row = blockIdx.x;
    const short* ar = attb + row * S;
    const short* mr = mixb + row * S;
    const int t = threadIdx.x;
    const int wave = t >> 6;

    bf16x8 a8 = *(const bf16x8*)&ar[t * 8];
    bf16x8 m8 = *(const bf16x8*)&mr[t * 8];
    float av[8], mv[8];
#pragma unroll
    for (int i = 0; i < 8; ++i) { av[i] = bf2f(a8[i]); mv[i] = bf2f(m8[i]); }

    float amax = av[0], mmax = mv[0];
#pragma unroll
    for (int i = 1; i < 8; ++i) { amax = fmaxf(amax, av[i]); mmax = fmaxf(mmax, mv[i]); }
#pragma unroll
    for (int o = 32; o; o >>= 1) {
        amax = fmaxf(amax, __shfl_xor(amax, o));
        mmax = fmaxf(mmax, __shfl_xor(mmax, o));
    }
    __shared__ float red[2][4];
    if ((t & 63) == 0) { red[0][wave] = amax; red[1][wave] = mmax; }
    __syncthreads();
    amax = fmaxf(fmaxf(red[0][0], red[0][1]), fmaxf(red[0][2], red[0][3]));
    mmax = fmaxf(fmaxf(red[1][0], red[1][1]), fmaxf(red[1][2], red[1][3]));

    float asum = 0.f, msum = 0.f;
#pragma unroll
    for (int i = 0; i < 8; ++i) {
        av[i] = __expf(av[i] - amax); asum += av[i];
        mv[i] = __expf(mv[i] - mmax); msum += mv[i];
    }
#pragma unroll
    for (int o = 32; o; o >>= 1) {
        asum += __shfl_xor(asum, o);
        msum += __shfl_xor(msum, o);
    }
    __shared__ float red2[2][4];
    if ((t & 63) == 0) { red2[0][wave] = asum; red2[1][wave] = msum; }
    __syncthreads();
    asum = red2[0][0] + red2[0][1] + red2[0][2] + red2[0][3];
    msum = red2[1][0] + red2[1][1] + red2[1][2] + red2[1][3];

    const float a1 = a1p[0];
    const float wm = a1 / msum;
    const float wa = (1.0f - a1) / asum;

    float o0[8];
    bf16x8 ob;
#pragma unroll
    for (int i = 0; i < 8; ++i) {
        float s = wm * mv[i] + wa * av[i];
        o0[i] = s;
        ob[i] = f2bf(s);
    }
    float4 f0, f1;
    f0.x = o0[0]; f0.y = o0[1]; f0.z = o0[2]; f0.w = o0[3];
    f1.x = o0[4]; f1.y = o0[5]; f1.z = o0[6]; f1.w = o0[7];
    *(float4*)&outF[row * S + t * 8] = f0;
    *(float4*)&outF[row * S + t * 8 + 4] = f1;
    *(bf16x8*)&outB[row * S + t * 8] = ob;
}

// LayerNorm over D=384 of (X + Y [+ Y2]); X fp32 or bf16 (XBF).
template<int WRITE_F, int WRITE_BF, int TWO_Y, int XBF>
__global__ __launch_bounds__(256) void ln_kernel(
    const void* __restrict__ Xv, const float* __restrict__ Yr,
    const float* __restrict__ Y2,
    const float* __restrict__ g, const float* __restrict__ be,
    float* __restrict__ outF, short* __restrict__ outB)
{
    const int Dm = 384;
    const int wave = threadIdx.x >> 6, lane = threadIdx.x & 63;
    const long long row = (long long)blockIdx.x * 4 + wave;
    const float* y = Yr + row * Dm;
    const float* y2 = TWO_Y ? (Y2 + row * Dm) : nullptr;
    float h[6];
    float s = 0.f, s2 = 0.f;
#pragma unroll
    for (int j = 0; j < 6; ++j) {
        int c = j * 64 + lane;
        float xv;
        if (XBF) xv = bf2f(((const short*)Xv)[row * Dm + c]);
        else     xv = ((const float*)Xv)[row * Dm + c];
        h[j] = xv + y[c];
        if (TWO_Y) h[j] += y2[c];
        s += h[j]; s2 += h[j] * h[j];
    }
#pragma unroll
    for (int o = 32; o; o >>= 1) { s += __shfl_xor(s, o); s2 += __shfl_xor(s2, o); }
    const float mean = s * (1.0f / 384.0f);
    const float var = s2 * (1.0f / 384.0f) - mean * mean;
    const float rstd = rsqrtf(var + 1e-5f);
#pragma unroll
    for (int j = 0; j < 6; ++j) {
        int c = j * 64 + lane;
        float v = (h[j] - mean) * rstd * g[c] + be[c];
        if (WRITE_F) outF[row * Dm + c] = v;
        if (WRITE_BF) outB[row * Dm + c] = f2bf(v);
    }
}

extern "C" void kernel_launch(void* const* d_in, const int* in_sizes, int n_in,
                              void* d_out, int out_size, void* d_ws, size_t ws_size,
                              hipStream_t stream) {
    const float* tgt     = (const float*)d_in[0];
    const float* memory  = (const float*)d_in[1];
    const float* a1      = (const float*)d_in[2];
    const float* score_c = (const float*)d_in[3];
    const float* out_c   = (const float*)d_in[4];
    const float* Wq = (const float*)d_in[5];  const float* bq = (const float*)d_in[6];
    const float* Wk = (const float*)d_in[7];  const float* bk = (const float*)d_in[8];
    const float* Wv = (const float*)d_in[9];  const float* bv = (const float*)d_in[10];
    const float* Wu = (const float*)d_in[11]; const float* bu = (const float*)d_in[12];
    const float* Wn = (const float*)d_in[13]; const float* bn = (const float*)d_in[14];
    const float* W1 = (const float*)d_in[15]; const float* b1 = (const float*)d_in[16];
    const float* W2 = (const float*)d_in[17]; const float* b2 = (const float*)d_in[18];
    const float* g1 = (const float*)d_in[19]; const float* be1 = (const float*)d_in[20];
    const float* g2 = (const float*)d_in[21]; const float* be2 = (const float*)d_in[22];

    const long long BT = 16384;            // B*T
    const long long S2 = 2048LL * 2048;    // per-batch score matrix elems
    const long long PB = 2048LL * 384;     // per-batch [2048,384] panel elems
    char* ws = (char*)d_ws;
    size_t off = 0;
    auto A_ = [&](size_t b) { size_t r = off; off += (b + 255) & ~(size_t)255; return r; };

    const size_t oTgtB  = A_(BT * 384 * 2);
    const size_t oMemB  = A_(BT * 256 * 2);
    const size_t oOutcB = A_(BT * 384 * 2);
    const size_t oWquT  = A_(768 * 384 * 2);
    const size_t oWnT   = A_(384 * 384 * 2);
    const size_t oWkT   = A_(384 * 256 * 2);
    const size_t oWvT   = A_(384 * 256 * 2);
    const size_t oW1T   = A_(1536 * 384 * 2);
    const size_t oW2T   = A_(384 * 1536 * 2);
    const size_t oQUb   = A_(768 * 4);
    const size_t oQU    = A_(16 * PB * 2);  // qu packed [16384, 768]
    const size_t oKP    = A_(16 * PB * 2);  // k (0-7), Pt (8-15)
    const size_t oVT    = A_(8LL * 384 * 2048 * 2);
    const size_t oJ     = A_(8 * S2 * 2);   // score_bf (blend output)
    const size_t oKr    = A_(8 * S2 * 2);   // z0|z1 fp32 halves
    const size_t oAM    = A_(16 * S2 * 2);  // knoT + ptH early; att|mixed; later h_bf / ff_f
    const size_t oXB    = A_(BT * 384 * 2);

    short* tgt_bf  = (short*)(ws + oTgtB);
    short* mem_bf  = (short*)(ws + oMemB);
    short* outc_bf = (short*)(ws + oOutcB);
    short* WquT = (short*)(ws + oWquT);
    short* WnT  = (short*)(ws + oWnT);
    short* WkT  = (short*)(ws + oWkT);
    short* WvT  = (short*)(ws + oWvT);
    short* W1T  = (short*)(ws + oW1T);
    short* W2T  = (short*)(ws + oW2T);
    float* qu_bias = (float*)(ws + oQUb);
    short* qu_bf  = (short*)(ws + oQU);
    short* k_bf   = (short*)(ws + oKP);
    short* Pt_bf  = k_bf + 8 * PB;
    short* vT_bf  = (short*)(ws + oVT);
    short* score_bf = (short*)(ws + oJ);
    float* z0_f     = (float*)(ws + oKr);
    float* z1_f     = z0_f + 6291456;
    short* knoT_bf  = (short*)(ws + oAM);   // alias: dead before att written
    float* ptH_f    = (float*)(ws + oAM + 32LL * 1024 * 1024);  // Pt fp32 halves, dead before att
    short* att_bf   = (short*)(ws + oAM);
    short* mix_bf   = att_bf + 8 * S2;
    short* h_bf     = (short*)(ws + oAM);               // alias (att dead after blend)
    float* ff_f     = (float*)(ws + oAM + 8 * S2 * 2);  // alias (mixed dead after blend)
    short* x_bf = (short*)(ws + oXB);

    float* outMain = (float*)d_out;
    float* outScore = (float*)d_out + 6291456;   // B*T*D elements

    const float SC = 0.05103103630798288f;  // 1/sqrt(384)
    dim3 blk(256);

    // prologue: casts + bias concat + weight transposes
    prologue<<<4541, blk, 0, stream>>>(
        tgt, memory, out_c, bq, bu, tgt_bf, mem_bf, outc_bf, qu_bias,
        Wq, Wk, Wv, Wu, Wn, W1, W2, WquT, WkT, WvT, WnT, W1T, W2T);

    // qu (bx 0-5) + k (bx 6-8) projections in one launch
    gemm128rr<<<dim3(9, 128, 1), blk, 0, stream>>>(
        tgt_bf, WquT, qu_bf, qu_bias, 384, 384, 384, 768,
        mem_bf, WkT, k_bf, bk, 256, 256, 256, 384);
    // vT (z 0-7) + knoT (z 8-15) merged
    gemm128pz<<<dim3(16, 3, 16), blk, 0, stream>>>(
        WvT, mem_bf, vT_bf, bv, 256, 256, 256, 2048, 2048LL * 256, PB,
        WnT, outc_bf, knoT_bf, bn, 384, 384, 384, 2048, PB, PB);
    // Pt = score_c^T @ knoT^T, TN GEMM, K-split x2 (zhi) into fp32 halves
    gemmTN<<<dim3(3, 16, 16), blk, 0, stream>>>(
        score_c, knoT_bf, ptH_f, S2, PB, PB, 6291456);
    combine_bf<<<6144, blk, 0, stream>>>(ptH_f, 6291456, Pt_bf);
    // att (z 0-7: q x k) + mixed (z 8-15: unk x Pt), 256^2 engine (L2-BW fix)
    gemmBig<<<dim3(8, 8, 16), dim3(512), 0, stream>>>(
        qu_bf, k_bf, att_bf, 384, 768, 384, 2048,
        2048LL * 768, PB, S2, 384, 8 * PB, 8 * S2, SC);
    // score = a1*softmax(mixed) + (1-a1)*softmax(att)
    softmax_blend<<<16384, blk, 0, stream>>>(att_bf, mix_bf, a1, outScore, score_bf);
    // z = score @ v, K split in two halves (z planes 8-15 do k in [1024,2048))
    gemm128r<0, 0, 0><<<dim3(3, 16, 16), blk, 0, stream>>>(
        score_bf, vT_bf, z0_f, nullptr, 1024, 2048, 2048, 384,
        S2, PB, PB, 1024, 1024, 6291456, 1.0f);
    // x = LN(tgt + z0 + z1) -> bf16 only
    ln_kernel<0, 1, 1, 0><<<4096, blk, 0, stream>>>(
        tgt, z0_f, z1_f, g1, be1, nullptr, x_bf);
    // FFN1
    gemm128r<1, 1, 1><<<dim3(12, 128, 1), blk, 0, stream>>>(
        x_bf, W1T, h_bf, b1, 384, 384, 384, 1536, 0, 0, 0, 0, 0, 0, 1.0f);
    // FFN2 (bias in GEMM)
    gemm128r<0, 1, 0><<<dim3(3, 128, 1), blk, 0, stream>>>(
        h_bf, W2T, ff_f, b2, 1536, 1536, 1536, 384, 0, 0, 0, 0, 0, 0, 1.0f);
    // out = LN(x + ff), x read as bf16
    ln_kernel<1, 0, 0, 1><<<4096, blk, 0, stream>>>(
        x_bf, ff_f, nullptr, g2, be2, outMain, nullptr);
}

// Round 19
// 421.900 us; speedup vs baseline: 1.0100x; 1.0088x over previous
//
#include <hip/hip_runtime.h>
#include <stdint.h>

typedef __attribute__((ext_vector_type(8))) short bf16x8;
typedef __attribute__((ext_vector_type(4))) short bf16x4;
typedef __attribute__((ext_vector_type(4))) float f32x4;

__device__ __forceinline__ short f2bf(float f) {
    union { float f; unsigned u; } v; v.f = f;
    unsigned r = v.u + 0x7fffu + ((v.u >> 16) & 1u);
    return (short)(r >> 16);
}
__device__ __forceinline__ float bf2f(short s) {
    union { unsigned u; float f; } v;
    v.u = ((unsigned)(unsigned short)s) << 16;
    return v.f;
}

__device__ __forceinline__ void gld16(const void* g, void* l) {
    auto gp = reinterpret_cast<const __attribute__((address_space(1))) unsigned int*>(
        reinterpret_cast<uintptr_t>(g));
    auto lp = reinterpret_cast<__attribute__((address_space(3))) unsigned int*>(
        reinterpret_cast<uintptr_t>(l));
    __builtin_amdgcn_global_load_lds(gp, lp, 16, 0, 0);
}

// ---------------------------------------------------------------------------
// gemmTN: Pt_half[s,d] = sum_{c in half} score_c[c,s] * knoT[d,c].
// (verified round 16) K-split x2 via zhi, fp32 partials, grid (3,16,16).
// ---------------------------------------------------------------------------
__global__ __launch_bounds__(256, 3) void gemmTN(
    const float* __restrict__ Ag, const short* __restrict__ Bg,
    float* __restrict__ Cg,
    long long sA, long long sB, long long sC, long long dC)
{
    __shared__ short lds[2 * 8256];   // per buf: A 4160 (8 quads x 520) | B 4096
    const int t = threadIdx.x;
    const int lane = t & 63;
    const int wave = t >> 6;
    const int wm = wave >> 1, wn = wave & 1;

    const int nwg = 3 * 16 * 16;
    int id = blockIdx.x + 3 * (blockIdx.y + 16 * blockIdx.z);
    id = (id & 7) * (nwg >> 3) + (id >> 3);
    const int bx = id % 3;
    const int by = (id / 3) % 16;
    const int bzz = id / 48;
    const int zlo = bzz & 7, zhi = bzz >> 3;

    const long long s0 = (long long)by * 128;
    const int d0 = bx * 128;
    const int q = t >> 5, kk = t & 31;
    const float* Asrc = Ag + zlo * sA + (long long)zhi * 1024 * 2048
                        + (long long)(q * 4) * 2048 + s0 + kk * 4;

    const int gk = ((t & 3) ^ ((t >> 2) & 3) ^ ((t >> 4) & 3)) * 8;
    const short* Bsrc = Bg + zlo * sB + zhi * 1024 + (d0 + (t >> 2)) * 2048LL + gk;

    const int frow = lane & 15;
    const int g = lane >> 4;
    const int fcol = (g ^ (frow & 3) ^ ((frow >> 2) & 3)) * 8;

    f32x4 acc[4][4] = {};
    f32x4 ar[4];

#define STAGE_B(BUF, KC) do { \
        gld16(Bsrc + (KC), &lds[(BUF) + 4160 + t * 8]); \
        gld16(Bsrc + (KC) + 64LL * 2048, &lds[(BUF) + 4160 + 2048 + t * 8]); } while (0)

#define WRITE_A(BUF) do { \
        short tmp[16]; \
        _Pragma("unroll") \
        for (int i = 0; i < 16; ++i) tmp[i] = f2bf(ar[i & 3][i >> 2]); \
        short* dst = &lds[(BUF) + q * 520 + kk * 16]; \
        *(bf16x8*)dst = *(bf16x8*)&tmp[0]; \
        *(bf16x8*)(dst + 8) = *(bf16x8*)&tmp[8]; } while (0)

#pragma unroll
    for (int r = 0; r < 4; ++r) ar[r] = *(const f32x4*)&Asrc[(long long)r * 2048];
    STAGE_B(0, 0);
    WRITE_A(0);
    asm volatile("s_waitcnt vmcnt(0) lgkmcnt(0)\ns_barrier" ::: "memory");
#pragma unroll
    for (int r = 0; r < 4; ++r) ar[r] = *(const f32x4*)&Asrc[65536LL + r * 2048];

    const int NT = 32;   // K-half = 1024, BK = 32
    for (int kt = 0; kt < NT; ++kt) {
        const int rb = (kt & 1) * 8256;
        const int wb = ((kt + 1) & 1) * 8256;

        bf16x8 av[4], bv[4];
#pragma unroll
        for (int m = 0; m < 4; ++m) {
            const int sl = (wm * 64 + m * 16 + frow) * 4;
            bf16x4 lo = *(const bf16x4*)&lds[rb + 1040 * g + sl];
            bf16x4 hi = *(const bf16x4*)&lds[rb + 1040 * g + 520 + sl];
            av[m] = __builtin_shufflevector(lo, hi, 0, 1, 2, 3, 4, 5, 6, 7);
        }
#pragma unroll
        for (int n = 0; n < 4; ++n)
            bv[n] = *(const bf16x8*)&lds[rb + 4160 + (wn * 64 + n * 16 + frow) * 32 + fcol];

        if (kt + 1 < NT) {
            STAGE_B(wb, (long long)(kt + 1) * 32);
            WRITE_A(wb);
        }
#pragma unroll
        for (int m = 0; m < 4; ++m)
#pragma unroll
            for (int n = 0; n < 4; ++n)
                acc[m][n] = __builtin_amdgcn_mfma_f32_16x16x32_bf16(av[m], bv[n], acc[m][n], 0, 0, 0);
        if (kt + 1 < NT) {
            asm volatile("s_waitcnt vmcnt(0) lgkmcnt(0)\ns_barrier" ::: "memory");
            if (kt + 2 < NT) {
#pragma unroll
                for (int r = 0; r < 4; ++r)
                    ar[r] = *(const f32x4*)&Asrc[(long long)(kt + 2) * 65536 + r * 2048];
            }
        }
    }
#undef STAGE_B
#undef WRITE_A

    const int crow = (lane >> 4) * 4;
    const int ccol = lane & 15;
    const long long cz = zlo * sC + zhi * dC;
#pragma unroll
    for (int m = 0; m < 4; ++m)
#pragma unroll
        for (int n = 0; n < 4; ++n)
#pragma unroll
            for (int i = 0; i < 4; ++i) {
                long long r = s0 + wm * 64 + m * 16 + crow + i;
                long long c = d0 + wn * 64 + n * 16 + ccol;
                Cg[cz + r * 384 + c] = acc[m][n][i];
            }
}

// combine K-split fp32 halves -> bf16: out[i] = bf16(p[i] + p[i+half])
__global__ __launch_bounds__(256) void combine_bf(
    const float* __restrict__ p, long long half, short* __restrict__ out)
{
    long long i = ((long long)blockIdx.x * 256 + threadIdx.x) * 4;
    if (i + 3 < half) {
        float4 a = *(const float4*)&p[i];
        float4 b = *(const float4*)&p[i + half];
        short4 o;
        o.x = f2bf(a.x + b.x); o.y = f2bf(a.y + b.y);
        o.z = f2bf(a.z + b.z); o.w = f2bf(a.w + b.w);
        *(short4*)&out[i] = o;
    }
}

// ---------------------------------------------------------------------------
// gemmWide: 128x256 NT GEMM, BK=32, 4 waves (2x2), wave-tile 64x128.
// Ring-3 LDS (72 KiB -> 2 blocks/CU), stage distance 2, counted vmcnt(6).
// GRID CONTRACT: gy*128 == rows PER BATCH-PLANE (z).
// ---------------------------------------------------------------------------
template<int OUTBF, int BIASMODE /*0 none,1 col*/, int DORELU>
__global__ __launch_bounds__(256, 2) void gemmWide(
    const short* __restrict__ Ag, const short* __restrict__ Bg,
    void* __restrict__ Cg, const float* __restrict__ bias,
    int K, int lda, int ldb, int ldc,
    long long sA, long long sB, long long sC,
    long long dA, long long dB, long long dC, float scale)
{
    __shared__ short lds[3 * 12288];
    const int t = threadIdx.x;
    const int lane = t & 63;
    const int wave = t >> 6;
    const int wm = wave >> 1, wn = wave & 1;

    const int gx = gridDim.x, gy = gridDim.y;
    const int nwg = gx * gy * gridDim.z;
    int id = blockIdx.x + gx * (blockIdx.y + gy * blockIdx.z);
    id = (id & 7) * (nwg >> 3) + (id >> 3);
    const int bx = id % gx;
    const int by = (id / gx) % gy;
    const int bz = id / (gx * gy);
    const int zlo = bz & 7, zhi = bz >> 3;

    const long long row0 = (long long)by * 128;
    const long long col0 = (long long)bx * 256;
    const int NT = K >> 5;

    const int gk = ((t & 3) ^ ((t >> 2) & 3) ^ ((t >> 4) & 3)) * 8;
    const short* Asrc = Ag + zlo * sA + zhi * dA + (row0 + (t >> 2)) * (long long)lda + gk;
    const short* Bsrc = Bg + zlo * sB + zhi * dB + (col0 + (t >> 2)) * (long long)ldb + gk;

    const int frow = lane & 15;
    const int fcol = ((lane >> 4) ^ (frow & 3) ^ ((frow >> 2) & 3)) * 8;

    f32x4 acc[4][8] = {};

#define STG(BUF, KC) do { \
        gld16(Asrc + (KC), &lds[(BUF) * 12288 + t * 8]); \
        gld16(Asrc + (KC) + 64LL * lda, &lds[(BUF) * 12288 + 2048 + t * 8]); \
        gld16(Bsrc + (KC), &lds[(BUF) * 12288 + 4096 + t * 8]); \
        gld16(Bsrc + (KC) + 64LL * ldb, &lds[(BUF) * 12288 + 6144 + t * 8]); \
        gld16(Bsrc + (KC) + 128LL * ldb, &lds[(BUF) * 12288 + 8192 + t * 8]); \
        gld16(Bsrc + (KC) + 192LL * ldb, &lds[(BUF) * 12288 + 10240 + t * 8]); } while (0)

    STG(0, 0);
    STG(1, 32);
    asm volatile("s_waitcnt vmcnt(6)\ns_barrier" ::: "memory");

    for (int kt = 0; kt < NT; ++kt) {
        const int rb = (kt % 3) * 12288;
        bf16x8 av[4], bv[8];
#pragma unroll
        for (int m = 0; m < 4; ++m)
            av[m] = *(const bf16x8*)&lds[rb + (wm * 64 + m * 16 + frow) * 32 + fcol];
#pragma unroll
        for (int n = 0; n < 8; ++n)
            bv[n] = *(const bf16x8*)&lds[rb + 4096 + (wn * 128 + n * 16 + frow) * 32 + fcol];
        if (kt + 2 < NT) STG((kt + 2) % 3, (long long)(kt + 2) * 32);
        __builtin_amdgcn_s_setprio(1);
#pragma unroll
        for (int m = 0; m < 4; ++m)
#pragma unroll
            for (int n = 0; n < 8; ++n)
                acc[m][n] = __builtin_amdgcn_mfma_f32_16x16x32_bf16(av[m], bv[n], acc[m][n], 0, 0, 0);
        __builtin_amdgcn_s_setprio(0);
        if (kt + 1 < NT) {
            if (kt + 2 < NT) asm volatile("s_waitcnt vmcnt(6)\ns_barrier" ::: "memory");
            else             asm volatile("s_waitcnt vmcnt(0)\ns_barrier" ::: "memory");
        }
    }
#undef STG

    const int crow = (lane >> 4) * 4;
    const int ccol = lane & 15;
    const long long cz = zlo * sC + zhi * dC;
#pragma unroll
    for (int m = 0; m < 4; ++m)
#pragma unroll
        for (int n = 0; n < 8; ++n)
#pragma unroll
            for (int i = 0; i < 4; ++i) {
                long long r = row0 + wm * 64 + m * 16 + crow + i;
                long long c = col0 + wn * 128 + n * 16 + ccol;
                float v = acc[m][n][i] * scale;
                if (BIASMODE == 1) v += bias[c];
                if (DORELU) v = fmaxf(v, 0.0f);
                long long idx = cz + r * (long long)ldc + c;
                if (OUTBF) ((short*)Cg)[idx] = f2bf(v);
                else ((float*)Cg)[idx] = v;
            }
}

// ---------------------------------------------------------------------------
// gemm128r: 128x128 NT GEMM, BK=32, ring-3 (verified round 7).
// ---------------------------------------------------------------------------
template<int OUTBF, int BIASMODE /*0 none,1 col,2 row*/, int DORELU>
__global__ __launch_bounds__(256, 3) void gemm128r(
    const short* __restrict__ Ag, const short* __restrict__ Bg,
    void* __restrict__ Cg, const float* __restrict__ bias,
    int K, int lda, int ldb, int ldc,
    long long sA, long long sB, long long sC,
    long long dA, long long dB, long long dC, float scale)
{
    __shared__ short lds[3 * 8192];
    const int t = threadIdx.x;
    const int lane = t & 63;
    const int wave = t >> 6;
    const int wm = wave >> 1, wn = wave & 1;

    const int gx = gridDim.x, gy = gridDim.y;
    const int nwg = gx * gy * gridDim.z;
    int id = blockIdx.x + gx * (blockIdx.y + gy * blockIdx.z);
    id = (id & 7) * (nwg >> 3) + (id >> 3);
    const int bx = id % gx;
    const int by = (id / gx) % gy;
    const int bz = id / (gx * gy);
    const int zlo = bz & 7, zhi = bz >> 3;

    const long long row0 = (long long)by * 128;
    const long long col0 = (long long)bx * 128;
    const int NT = K >> 5;

    const int gk = ((t & 3) ^ ((t >> 2) & 3) ^ ((t >> 4) & 3)) * 8;
    const short* Asrc = Ag + zlo * sA + zhi * dA + (row0 + (t >> 2)) * (long long)lda + gk;
    const short* Bsrc = Bg + zlo * sB + zhi * dB + (col0 + (t >> 2)) * (long long)ldb + gk;

    const int frow = lane & 15;
    const int fcol = ((lane >> 4) ^ (frow & 3) ^ ((frow >> 2) & 3)) * 8;

    f32x4 acc[4][4] = {};

#define STG(BUF, KC) do { \
        gld16(Asrc + (KC), &lds[(BUF) * 8192 + t * 8]); \
        gld16(Asrc + (KC) + 64LL * lda, &lds[(BUF) * 8192 + 2048 + t * 8]); \
        gld16(Bsrc + (KC), &lds[(BUF) * 8192 + 4096 + t * 8]); \
        gld16(Bsrc + (KC) + 64LL * ldb, &lds[(BUF) * 8192 + 6144 + t * 8]); } while (0)

    STG(0, 0);
    STG(1, 32);
    asm volatile("s_waitcnt vmcnt(4)\ns_barrier" ::: "memory");

    for (int kt = 0; kt < NT; ++kt) {
        const int rb = (kt % 3) * 8192;
        bf16x8 av[4], bv[4];
#pragma unroll
        for (int m = 0; m < 4; ++m)
            av[m] = *(const bf16x8*)&lds[rb + (wm * 64 + m * 16 + frow) * 32 + fcol];
#pragma unroll
        for (int n = 0; n < 4; ++n)
            bv[n] = *(const bf16x8*)&lds[rb + 4096 + (wn * 64 + n * 16 + frow) * 32 + fcol];
        if (kt + 2 < NT) STG((kt + 2) % 3, (long long)(kt + 2) * 32);
        __builtin_amdgcn_s_setprio(1);
#pragma unroll
        for (int m = 0; m < 4; ++m)
#pragma unroll
            for (int n = 0; n < 4; ++n)
                acc[m][n] = __builtin_amdgcn_mfma_f32_16x16x32_bf16(av[m], bv[n], acc[m][n], 0, 0, 0);
        __builtin_amdgcn_s_setprio(0);
        if (kt + 1 < NT) {
            if (kt + 2 < NT) asm volatile("s_waitcnt vmcnt(4)\ns_barrier" ::: "memory");
            else             asm volatile("s_waitcnt vmcnt(0)\ns_barrier" ::: "memory");
        }
    }
#undef STG

    const int crow = (lane >> 4) * 4;
    const int ccol = lane & 15;
    const long long cz = zlo * sC + zhi * dC;
#pragma unroll
    for (int m = 0; m < 4; ++m)
#pragma unroll
        for (int n = 0; n < 4; ++n)
#pragma unroll
            for (int i = 0; i < 4; ++i) {
                long long r = row0 + wm * 64 + m * 16 + crow + i;
                long long c = col0 + wn * 64 + n * 16 + ccol;
                float v = acc[m][n][i] * scale;
                if (BIASMODE == 1) v += bias[c];
                if (BIASMODE == 2) v += bias[r];
                if (DORELU) v = fmaxf(v, 0.0f);
                long long idx = cz + r * (long long)ldc + c;
                if (OUTBF) ((short*)Cg)[idx] = f2bf(v);
                else ((float*)Cg)[idx] = v;
            }
}

// ---------------------------------------------------------------------------
// gemm128rr: bx-keyed dual 128r (qu: bx<6, k: bx>=6). Grid (9,128,1).
// ---------------------------------------------------------------------------
__global__ __launch_bounds__(256, 3) void gemm128rr(
    const short* __restrict__ A1, const short* __restrict__ B1,
    short* __restrict__ C1, const float* __restrict__ bias1,
    int K1, int lda1, int ldb1, int ldc1,
    const short* __restrict__ A2, const short* __restrict__ B2,
    short* __restrict__ C2, const float* __restrict__ bias2,
    int K2, int lda2, int ldb2, int ldc2)
{
    __shared__ short lds[3 * 8192];
    const int t = threadIdx.x;
    const int lane = t & 63;
    const int wave = t >> 6;
    const int wm = wave >> 1, wn = wave & 1;

    const int gx = gridDim.x, gy = gridDim.y;
    const int nwg = gx * gy;
    int id = blockIdx.x + gx * blockIdx.y;
    id = (id & 7) * (nwg >> 3) + (id >> 3);
    const int bx = id % gx;
    const int by = id / gx;

    const bool sel = bx >= 6;
    const int bxx = sel ? bx - 6 : bx;
    const short* Ag = sel ? A2 : A1;
    const short* Bg = sel ? B2 : B1;
    short* Cg = sel ? C2 : C1;
    const float* bias = sel ? bias2 : bias1;
    const int K = sel ? K2 : K1;
    const int lda = sel ? lda2 : lda1;
    const int ldb = sel ? ldb2 : ldb1;
    const int ldc = sel ? ldc2 : ldc1;

    const long long row0 = (long long)by * 128;
    const long long col0 = (long long)bxx * 128;
    const int NT = K >> 5;

    const int gk = ((t & 3) ^ ((t >> 2) & 3) ^ ((t >> 4) & 3)) * 8;
    const short* Asrc = Ag + (row0 + (t >> 2)) * (long long)lda + gk;
    const short* Bsrc = Bg + (col0 + (t >> 2)) * (long long)ldb + gk;

    const int frow = lane & 15;
    const int fcol = ((lane >> 4) ^ (frow & 3) ^ ((frow >> 2) & 3)) * 8;

    f32x4 acc[4][4] = {};

#define STG(BUF, KC) do { \
        gld16(Asrc + (KC), &lds[(BUF) * 8192 + t * 8]); \
        gld16(Asrc + (KC) + 64LL * lda, &lds[(BUF) * 8192 + 2048 + t * 8]); \
        gld16(Bsrc + (KC), &lds[(BUF) * 8192 + 4096 + t * 8]); \
        gld16(Bsrc + (KC) + 64LL * ldb, &lds[(BUF) * 8192 + 6144 + t * 8]); } while (0)

    STG(0, 0);
    STG(1, 32);
    asm volatile("s_waitcnt vmcnt(4)\ns_barrier" ::: "memory");

    for (int kt = 0; kt < NT; ++kt) {
        const int rb = (kt % 3) * 8192;
        bf16x8 av[4], bv[4];
#pragma unroll
        for (int m = 0; m < 4; ++m)
            av[m] = *(const bf16x8*)&lds[rb + (wm * 64 + m * 16 + frow) * 32 + fcol];
#pragma unroll
        for (int n = 0; n < 4; ++n)
            bv[n] = *(const bf16x8*)&lds[rb + 4096 + (wn * 64 + n * 16 + frow) * 32 + fcol];
        if (kt + 2 < NT) STG((kt + 2) % 3, (long long)(kt + 2) * 32);
        __builtin_amdgcn_s_setprio(1);
#pragma unroll
        for (int m = 0; m < 4; ++m)
#pragma unroll
            for (int n = 0; n < 4; ++n)
                acc[m][n] = __builtin_amdgcn_mfma_f32_16x16x32_bf16(av[m], bv[n], acc[m][n], 0, 0, 0);
        __builtin_amdgcn_s_setprio(0);
        if (kt + 1 < NT) {
            if (kt + 2 < NT) asm volatile("s_waitcnt vmcnt(4)\ns_barrier" ::: "memory");
            else             asm volatile("s_waitcnt vmcnt(0)\ns_barrier" ::: "memory");
        }
    }
#undef STG

    const int crow = (lane >> 4) * 4;
    const int ccol = lane & 15;
#pragma unroll
    for (int m = 0; m < 4; ++m)
#pragma unroll
        for (int n = 0; n < 4; ++n)
#pragma unroll
            for (int i = 0; i < 4; ++i) {
                long long r = row0 + wm * 64 + m * 16 + crow + i;
                long long c = col0 + wn * 64 + n * 16 + ccol;
                float v = acc[m][n][i] + bias[c];
                Cg[r * (long long)ldc + c] = f2bf(v);
            }
}

// ---------------------------------------------------------------------------
// gemm128pz: dual-parameter 2-phase engine (verified round 6), z<8 -> vT,
// z>=8 -> knoT. Both: C = A @ B^T + rowbias, A = weight.
// ---------------------------------------------------------------------------
#define RD_A(RB, M, KS) (*(const bf16x8*)&lds[(RB) + (wm * 64 + (M) * 16 + frow) * 64 + \
        ((((KS) << 2) | fq) ^ (frow & 7)) * 8])
#define RD_B(RB, Nn, KS) (*(const bf16x8*)&lds[(RB) + 8192 + (wn * 64 + (Nn) * 16 + frow) * 64 + \
        ((((KS) << 2) | fq) ^ (frow & 7)) * 8])

__global__ __launch_bounds__(256, 2) void gemm128pz(
    const short* __restrict__ A1, const short* __restrict__ B1, short* __restrict__ C1,
    const float* __restrict__ bias1, int K1, int lda1, int ldb1, int ldc1,
    long long sB1, long long sC1,
    const short* __restrict__ A2, const short* __restrict__ B2, short* __restrict__ C2,
    const float* __restrict__ bias2, int K2, int lda2, int ldb2, int ldc2,
    long long sB2, long long sC2)
{
    __shared__ short lds[2 * 16384];
    const int t = threadIdx.x;
    const int lane = t & 63;
    const int wave = t >> 6;
    const int wm = wave >> 1, wn = wave & 1;

    const int gx = gridDim.x, gy = gridDim.y;
    const int nwg = gx * gy * gridDim.z;
    int id = blockIdx.x + gx * (blockIdx.y + gy * blockIdx.z);
    id = (id & 7) * (nwg >> 3) + (id >> 3);
    const int bx = id % gx;
    const int by = (id / gx) % gy;
    const int bz = id / (gx * gy);

    const bool sel = bz >= 8;
    const int zz = bz & 7;
    const short* Ag = sel ? A2 : A1;
    const short* Bg = sel ? B2 : B1;
    short* Cg = sel ? C2 : C1;
    const float* bias = sel ? bias2 : bias1;
    const int K = sel ? K2 : K1;
    const int lda = sel ? lda2 : lda1;
    const int ldb = sel ? ldb2 : ldb1;
    const int ldc = sel ? ldc2 : ldc1;
    const long long sB = sel ? sB2 : sB1;
    const long long sC = sel ? sC2 : sC1;

    const long long row0 = (long long)by * 128;
    const long long col0 = (long long)bx * 128;
    const int NT = K >> 6;

    const int srow = t >> 3;
    const int gk = ((t & 7) ^ (srow & 7)) * 8;
    const short* Asrc = Ag + (row0 + srow) * (long long)lda + gk;
    const short* Bsrc = Bg + (long long)zz * sB + (col0 + srow) * (long long)ldb + gk;

    const int frow = lane & 15;
    const int fq = lane >> 4;

    f32x4 acc[4][4] = {};

#define STAGE_A(WB, KC) do { _Pragma("unroll") \
        for (int r = 0; r < 4; ++r) \
            gld16(Asrc + (KC) + (long long)r * 32 * lda, &lds[(WB) + t * 8 + r * 2048]); } while (0)
#define STAGE_B(WB, KC) do { _Pragma("unroll") \
        for (int r = 0; r < 4; ++r) \
            gld16(Bsrc + (KC) + (long long)r * 32 * ldb, &lds[(WB) + 8192 + t * 8 + r * 2048]); } while (0)

    STAGE_A(0, 0);
    STAGE_B(0, 0);
    asm volatile("s_waitcnt vmcnt(0)\ns_barrier" ::: "memory");

    for (int kt = 0; kt < NT; ++kt) {
        const int rb = (kt & 1) << 14;
        const int wb = ((kt + 1) & 1) << 14;
        const bool st = (kt + 1) < NT;
        const long long kc = (long long)(kt + 1) << 6;

        bf16x8 av[4], bv[4];

#pragma unroll
        for (int m = 0; m < 4; ++m) av[m] = RD_A(rb, m, 0);
#pragma unroll
        for (int n = 0; n < 4; ++n) bv[n] = RD_B(rb, n, 0);
        if (st) STAGE_A(wb, kc);
        asm volatile("s_barrier" ::: "memory");
        __builtin_amdgcn_s_setprio(1);
#pragma unroll
        for (int m = 0; m < 4; ++m)
#pragma unroll
            for (int n = 0; n < 4; ++n)
                acc[m][n] = __builtin_amdgcn_mfma_f32_16x16x32_bf16(av[m], bv[n], acc[m][n], 0, 0, 0);
        __builtin_amdgcn_s_setprio(0);
        asm volatile("s_barrier" ::: "memory");

#pragma unroll
        for (int m = 0; m < 4; ++m) av[m] = RD_A(rb, m, 1);
#pragma unroll
        for (int n = 0; n < 4; ++n) bv[n] = RD_B(rb, n, 1);
        if (st) STAGE_B(wb, kc);
        asm volatile("s_barrier" ::: "memory");
        __builtin_amdgcn_s_setprio(1);
#pragma unroll
        for (int m = 0; m < 4; ++m)
#pragma unroll
            for (int n = 0; n < 4; ++n)
                acc[m][n] = __builtin_amdgcn_mfma_f32_16x16x32_bf16(av[m], bv[n], acc[m][n], 0, 0, 0);
        __builtin_amdgcn_s_setprio(0);
        if (st) asm volatile("s_waitcnt vmcnt(0)\ns_barrier" ::: "memory");
        else    asm volatile("s_barrier" ::: "memory");
    }
#undef STAGE_A
#undef STAGE_B

    const int crow = (lane >> 4) * 4;
    const int ccol = lane & 15;
    const long long cz = (long long)zz * sC;
#pragma unroll
    for (int m = 0; m < 4; ++m)
#pragma unroll
        for (int n = 0; n < 4; ++n)
#pragma unroll
            for (int i = 0; i < 4; ++i) {
                long long r = row0 + wm * 64 + m * 16 + crow + i;
                long long c = col0 + wn * 64 + n * 16 + ccol;
                float v = acc[m][n][i] + bias[r];
                Cg[cz + r * (long long)ldc + c] = f2bf(v);
            }
}
#undef RD_A
#undef RD_B

// ---------------------------------------------------------------------------
// prologue v3: [0,4096) cast 4xfloat4/thread | 4096 bias | [4097,4541) weight
// transposes (64x64). score_c transpose ELIMINATED (gemmTN reads it directly).
// ---------------------------------------------------------------------------
__global__ __launch_bounds__(256) void prologue(
    const float* __restrict__ tgt, const float* __restrict__ mem, const float* __restrict__ outc,
    const float* __restrict__ bq, const float* __restrict__ bu,
    short* __restrict__ tgtb, short* __restrict__ memb, short* __restrict__ outcb,
    float* __restrict__ qubias,
    const float* __restrict__ Wq, const float* __restrict__ Wk, const float* __restrict__ Wv,
    const float* __restrict__ Wu, const float* __restrict__ Wn,
    const float* __restrict__ W1, const float* __restrict__ W2,
    short* __restrict__ WquT, short* __restrict__ WkT, short* __restrict__ WvT,
    short* __restrict__ WnT, short* __restrict__ W1T, short* __restrict__ W2T)
{
    __shared__ float tile[64][65];
    const int blk = blockIdx.x;
    const int t = threadIdx.x;

    if (blk < 4096) {
        const long long R1 = 1572864;
        const long long R2 = R1 + 1048576;
        const long long base = (long long)blk * 1024 + t;
#pragma unroll
        for (int s = 0; s < 4; ++s) {
            long long i = base + s * 256;
            const float* in; short* out; long long j;
            if (i < R1) { in = tgt; out = tgtb; j = i; }
            else if (i < R2) { in = mem; out = memb; j = i - R1; }
            else { in = outc; out = outcb; j = i - R2; }
            float4 v = ((const float4*)in)[j];
            short4 o;
            o.x = f2bf(v.x); o.y = f2bf(v.y); o.z = f2bf(v.z); o.w = f2bf(v.w);
            ((short4*)out)[j] = o;
        }
        return;
    }

    if (blk == 4096) {
        if (t < 192)
            ((float4*)qubias)[t] = (t < 96) ? ((const float4*)bq)[t] : ((const float4*)bu)[t - 96];
        return;
    }

    // weight transposes (444 tiles of 64x64)
    int b = blk - 4097;
    const float* in; short* out; int R, C, local;
    if (b < 36)       { in = Wq; out = WquT;          R = 384;  C = 384;  local = b; }
    else if (b < 60)  { in = Wk; out = WkT;           R = 256;  C = 384;  local = b - 36; }
    else if (b < 84)  { in = Wv; out = WvT;           R = 256;  C = 384;  local = b - 60; }
    else if (b < 120) { in = Wu; out = WquT + 147456; R = 384;  C = 384;  local = b - 84; }
    else if (b < 156) { in = Wn; out = WnT;           R = 384;  C = 384;  local = b - 120; }
    else if (b < 300) { in = W1; out = W1T;           R = 384;  C = 1536; local = b - 156; }
    else              { in = W2; out = W2T;           R = 1536; C = 384;  local = b - 300; }
    const int nbx = C >> 6;
    const int r0 = (local / nbx) * 64, c0 = (local % nbx) * 64;
    const int lr = t >> 6, lc = t & 63;
#pragma unroll
    for (int i = 0; i < 16; ++i) {
        int r = lr * 16 + i;
        tile[r][lc] = in[(long long)(r0 + r) * C + c0 + lc];
    }
    __syncthreads();
#pragma unroll
    for (int i = 0; i < 16; ++i) {
        int r = lr * 16 + i;
        out[(long long)(c0 + r) * R + r0 + lc] = f2bf(tile[lc][r]);
    }
}

// blended dual softmax over rows of length 2048
__global__ __launch_bounds__(256) void softmax_blend(
    const short* __restrict__ attb, const short* __restrict__ mixb,
    const float* __restrict__ a1p,
    float* __restrict__ outF, short* __restrict__ outB)
{
    const int S = 2048;
    const long long row = blockIdx.x;
    const short* ar = attb + row * S;
    const short* mr = mixb + row * S;
    const int t = threadIdx.x;
    const int wave = t >> 6;

    bf16x8 a8 = *(const bf16x8*)&ar[t * 8];
    bf16x8 m8 = *(const bf16x8*)&mr[t * 8];
    float av[8], mv[8];
#pragma unroll
    for (int i = 0; i < 8; ++i) { av[i] = bf2f(a8[i]); mv[i] = bf2f(m8[i]); }

    float amax = av[0], mmax = mv[0];
#pragma unroll
    for (int i = 1; i < 8; ++i) { amax = fmaxf(amax, av[i]); mmax = fmaxf(mmax, mv[i]); }
#pragma unroll
    for (int o = 32; o; o >>= 1) {
        amax = fmaxf(amax, __shfl_xor(amax, o));
        mmax = fmaxf(mmax, __shfl_xor(mmax, o));
    }
    __shared__ float red[2][4];
    if ((t & 63) == 0) { red[0][wave] = amax; red[1][wave] = mmax; }
    __syncthreads();
    amax = fmaxf(fmaxf(red[0][0], red[0][1]), fmaxf(red[0][2], red[0][3]));
    mmax = fmaxf(fmaxf(red[1][0], red[1][1]), fmaxf(red[1][2], red[1][3]));

    float asum = 0.f, msum = 0.f;
#pragma unroll
    for (int i = 0; i < 8; ++i) {
        av[i] = __expf(av[i] - amax); asum += av[i];
        mv[i] = __expf(mv[i] - mmax); msum += mv[i];
    }
#pragma unroll
    for (int o = 32; o; o >>= 1) {
        asum += __shfl_xor(asum, o);
        msum += __shfl_xor(msum, o);
    }
    __shared__ float red2[2][4];
    if ((t & 63) == 0) { red2[0][wave] = asum; red2[1][wave] = msum; }
    __syncthreads();
    asum = red2[0][0] + red2[0][1] + red2[0][2] + red2[0][3];
    msum = red2[1][0] + red2[1][1] + red2[1][2] + red2[1][3];

    const float a1 = a1p[0];
    const float wm = a1 / msum;
    const float wa = (1.0f - a1) / asum;

    float o0[8];
    bf16x8 ob;
#pragma unroll
    for (int i = 0; i < 8; ++i) {
        float s = wm * mv[i] + wa * av[i];
        o0[i] = s;
        ob[i] = f2bf(s);
    }
    float4 f0, f1;
    f0.x = o0[0]; f0.y = o0[1]; f0.z = o0[2]; f0.w = o0[3];
    f1.x = o0[4]; f1.y = o0[5]; f1.z = o0[6]; f1.w = o0[7];
    *(float4*)&outF[row * S + t * 8] = f0;
    *(float4*)&outF[row * S + t * 8 + 4] = f1;
    *(bf16x8*)&outB[row * S + t * 8] = ob;
}

// LayerNorm over D=384 of (X + Y [+ Y2]); X fp32 or bf16 (XBF).
template<int WRITE_F, int WRITE_BF, int TWO_Y, int XBF>
__global__ __launch_bounds__(256) void ln_kernel(
    const void* __restrict__ Xv, const float* __restrict__ Yr,
    const float* __restrict__ Y2,
    const float* __restrict__ g, const float* __restrict__ be,
    float* __restrict__ outF, short* __restrict__ outB)
{
    const int Dm = 384;
    const int wave = threadIdx.x >> 6, lane = threadIdx.x & 63;
    const long long row = (long long)blockIdx.x * 4 + wave;
    const float* y = Yr + row * Dm;
    const float* y2 = TWO_Y ? (Y2 + row * Dm) : nullptr;
    float h[6];
    float s = 0.f, s2 = 0.f;
#pragma unroll
    for (int j = 0; j < 6; ++j) {
        int c = j * 64 + lane;
        float xv;
        if (XBF) xv = bf2f(((const short*)Xv)[row * Dm + c]);
        else     xv = ((const float*)Xv)[row * Dm + c];
        h[j] = xv + y[c];
        if (TWO_Y) h[j] += y2[c];
        s += h[j]; s2 += h[j] * h[j];
    }
#pragma unroll
    for (int o = 32; o; o >>= 1) { s += __shfl_xor(s, o); s2 += __shfl_xor(s2, o); }
    const float mean = s * (1.0f / 384.0f);
    const float var = s2 * (1.0f / 384.0f) - mean * mean;
    const float rstd = rsqrtf(var + 1e-5f);
#pragma unroll
    for (int j = 0; j < 6; ++j) {
        int c = j * 64 + lane;
        float v = (h[j] - mean) * rstd * g[c] + be[c];
        if (WRITE_F) outF[row * Dm + c] = v;
        if (WRITE_BF) outB[row * Dm + c] = f2bf(v);
    }
}

extern "C" void kernel_launch(void* const* d_in, const int* in_sizes, int n_in,
                              void* d_out, int out_size, void* d_ws, size_t ws_size,
                              hipStream_t stream) {
    const float* tgt     = (const float*)d_in[0];
    const float* memory  = (const float*)d_in[1];
    const float* a1      = (const float*)d_in[2];
    const float* score_c = (const float*)d_in[3];
    const float* out_c   = (const float*)d_in[4];
    const float* Wq = (const float*)d_in[5];  const float* bq = (const float*)d_in[6];
    const float* Wk = (const float*)d_in[7];  const float* bk = (const float*)d_in[8];
    const float* Wv = (const float*)d_in[9];  const float* bv = (const float*)d_in[10];
    const float* Wu = (const float*)d_in[11]; const float* bu = (const float*)d_in[12];
    const float* Wn = (const float*)d_in[13]; const float* bn = (const float*)d_in[14];
    const float* W1 = (const float*)d_in[15]; const float* b1 = (const float*)d_in[16];
    const float* W2 = (const float*)d_in[17]; const float* b2 = (const float*)d_in[18];
    const float* g1 = (const float*)d_in[19]; const float* be1 = (const float*)d_in[20];
    const float* g2 = (const float*)d_in[21]; const float* be2 = (const float*)d_in[22];

    const long long BT = 16384;            // B*T
    const long long S2 = 2048LL * 2048;    // per-batch score matrix elems
    const long long PB = 2048LL * 384;     // per-batch [2048,384] panel elems
    char* ws = (char*)d_ws;
    size_t off = 0;
    auto A_ = [&](size_t b) { size_t r = off; off += (b + 255) & ~(size_t)255; return r; };

    const size_t oTgtB  = A_(BT * 384 * 2);
    const size_t oMemB  = A_(BT * 256 * 2);
    const size_t oOutcB = A_(BT * 384 * 2);
    const size_t oWquT  = A_(768 * 384 * 2);
    const size_t oWnT   = A_(384 * 384 * 2);
    const size_t oWkT   = A_(384 * 256 * 2);
    const size_t oWvT   = A_(384 * 256 * 2);
    const size_t oW1T   = A_(1536 * 384 * 2);
    const size_t oW2T   = A_(384 * 1536 * 2);
    const size_t oQUb   = A_(768 * 4);
    const size_t oQU    = A_(16 * PB * 2);  // qu packed [16384, 768]
    const size_t oKP    = A_(16 * PB * 2);  // k (0-7), Pt (8-15)
    const size_t oVT    = A_(8LL * 384 * 2048 * 2);
    const size_t oJ     = A_(8 * S2 * 2);   // score_bf (blend output)
    const size_t oKr    = A_(8 * S2 * 2);   // z0|z1 fp32 halves
    const size_t oAM    = A_(16 * S2 * 2);  // knoT + ptH early; att|mixed; later h_bf / ff_f
    const size_t oXB    = A_(BT * 384 * 2);

    short* tgt_bf  = (short*)(ws + oTgtB);
    short* mem_bf  = (short*)(ws + oMemB);
    short* outc_bf = (short*)(ws + oOutcB);
    short* WquT = (short*)(ws + oWquT);
    short* WnT  = (short*)(ws + oWnT);
    short* WkT  = (short*)(ws + oWkT);
    short* WvT  = (short*)(ws + oWvT);
    short* W1T  = (short*)(ws + oW1T);
    short* W2T  = (short*)(ws + oW2T);
    float* qu_bias = (float*)(ws + oQUb);
    short* qu_bf  = (short*)(ws + oQU);
    short* k_bf   = (short*)(ws + oKP);
    short* Pt_bf  = k_bf + 8 * PB;
    short* vT_bf  = (short*)(ws + oVT);
    short* score_bf = (short*)(ws + oJ);
    float* z0_f     = (float*)(ws + oKr);
    float* z1_f     = z0_f + 6291456;
    short* knoT_bf  = (short*)(ws + oAM);   // alias: dead before att written
    float* ptH_f    = (float*)(ws + oAM + 32LL * 1024 * 1024);  // Pt fp32 halves, dead before att
    short* att_bf   = (short*)(ws + oAM);
    short* mix_bf   = att_bf + 8 * S2;
    short* h_bf     = (short*)(ws + oAM);               // alias (att dead after blend)
    float* ff_f     = (float*)(ws + oAM + 8 * S2 * 2);  // alias (mixed dead after blend)
    short* x_bf = (short*)(ws + oXB);

    float* outMain = (float*)d_out;
    float* outScore = (float*)d_out + 6291456;   // B*T*D elements

    const float SC = 0.05103103630798288f;  // 1/sqrt(384)
    dim3 blk(256);

    // prologue: casts + bias concat + weight transposes
    prologue<<<4541, blk, 0, stream>>>(
        tgt, memory, out_c, bq, bu, tgt_bf, mem_bf, outc_bf, qu_bias,
        Wq, Wk, Wv, Wu, Wn, W1, W2, WquT, WkT, WvT, WnT, W1T, W2T);

    // qu (bx 0-5) + k (bx 6-8) projections in one launch
    gemm128rr<<<dim3(9, 128, 1), blk, 0, stream>>>(
        tgt_bf, WquT, qu_bf, qu_bias, 384, 384, 384, 768,
        mem_bf, WkT, k_bf, bk, 256, 256, 256, 384);
    // vT (z 0-7) + knoT (z 8-15) merged
    gemm128pz<<<dim3(16, 3, 16), blk, 0, stream>>>(
        WvT, mem_bf, vT_bf, bv, 256, 256, 256, 2048, 2048LL * 256, PB,
        WnT, outc_bf, knoT_bf, bn, 384, 384, 384, 2048, PB, PB);
    // Pt = score_c^T @ knoT^T, TN GEMM, K-split x2 (zhi) into fp32 halves
    gemmTN<<<dim3(3, 16, 16), blk, 0, stream>>>(
        score_c, knoT_bf, ptH_f, S2, PB, PB, 6291456);
    combine_bf<<<6144, blk, 0, stream>>>(ptH_f, 6291456, Pt_bf);
    // att (z 0-7: q x k) + mixed (z 8-15: unk x Pt), wide engine
    gemmWide<1, 0, 0><<<dim3(8, 16, 16), blk, 0, stream>>>(
        qu_bf, k_bf, att_bf, nullptr, 384, 768, 384, 2048,
        2048LL * 768, PB, S2, 384, 8 * PB, 8 * S2, SC);
    // score = a1*softmax(mixed) + (1-a1)*softmax(att)
    softmax_blend<<<16384, blk, 0, stream>>>(att_bf, mix_bf, a1, outScore, score_bf);
    // z = score @ v, K split in two halves (z planes 8-15 do k in [1024,2048))
    gemm128r<0, 0, 0><<<dim3(3, 16, 16), blk, 0, stream>>>(
        score_bf, vT_bf, z0_f, nullptr, 1024, 2048, 2048, 384,
        S2, PB, PB, 1024, 1024, 6291456, 1.0f);
    // x = LN(tgt + z0 + z1) -> bf16 only
    ln_kernel<0, 1, 1, 0><<<4096, blk, 0, stream>>>(
        tgt, z0_f, z1_f, g1, be1, nullptr, x_bf);
    // FFN1
    gemm128r<1, 1, 1><<<dim3(12, 128, 1), blk, 0, stream>>>(
        x_bf, W1T, h_bf, b1, 384, 384, 384, 1536, 0, 0, 0, 0, 0, 0, 1.0f);
    // FFN2 (bias in GEMM)
    gemm128r<0, 1, 0><<<dim3(3, 128, 1), blk, 0, stream>>>(
        h_bf, W2T, ff_f, b2, 1536, 1536, 1536, 384, 0, 0, 0, 0, 0, 0, 1.0f);
    // out = LN(x + ff), x read as bf16
    ln_kernel<1, 0, 0, 1><<<4096, blk, 0, stream>>>(
        x_bf, ff_f, nullptr, g2, be2, outMain, nullptr);
}